// Round 4
// baseline (3242.051 us; speedup 1.0000x reference)
//
#include <hip/hip_runtime.h>
#include <math.h>

namespace {
constexpr int B_ = 2, CIN = 8, H_ = 224, W_ = 224;
constexpr int K_ = 7;
constexpr int F_ = 64, E_ = 8;
constexpr int N1 = 43, N2 = 43, N_ = N1 * N2;   // 1849
constexpr int M_ = 49;                           // candidates per query
constexpr int D_ = 800;                          // patch dim (C*P*P)
constexpr int HW = H_ * W_;
constexpr int NSW = 1856;                        // swizzled grid for n (8*232)

// workspace layout (floats).
constexpr size_t FHW = (size_t)B_ * F_ * HW;     // 6,422,528
constexpr size_t OFF_H1E = 0;
constexpr size_t OFF_H1T = OFF_H1E + FHW;
constexpr size_t OFF_H2E = OFF_H1T + FHW;
constexpr size_t OFF_H2T = OFF_H2E + FHW;
constexpr size_t OFF_WK  = 0;                                  // B*N*343
constexpr size_t OFF_NB  = 1280000;                            // > Wk end
constexpr size_t OFF_XE  = OFF_H2T + FHW;
constexpr size_t OFF_LTM = OFF_XE + (size_t)B_ * E_ * HW;
constexpr size_t OFF_PE  = OFF_LTM + (size_t)B_ * HW;
constexpr size_t OFF_YP  = OFF_PE + (size_t)B_ * N_ * D_;
constexpr size_t OFF_LT  = OFF_YP + (size_t)B_ * N_ * D_;
constexpr size_t OFF_SQ  = OFF_LT + (size_t)B_ * N_;

__device__ __forceinline__ int clampi(int v, int lo, int hi) {
  return min(max(v, lo), hi);
}
__device__ __forceinline__ int swiz_n(int xr) { return (xr & 7) * 232 + (xr >> 3); }
} // namespace

// ---------------------------------------------------------------------------
// 3x3 SAME conv, NCHW, 32x32 tile, 256 threads (4 waves). Each wave owns 2
// output channels; each lane owns a 4x4 pixel patch (ry=lane>>3, cx=lane&7).
// Input planes staged CIB=4/round in LDS with padded stride 36 + left halo so
// each lane reads its 6x6 window as 6x(b128+b64). Weights are wave-uniform ->
// scalar loads from global (no LDS), prefetch-covered by 288 FMAs/ci.
// NCOUT = valid output channels in this block (<=8); cout = channel stride.
// ---------------------------------------------------------------------------
template <int CI, int NCOUT, bool RELU>
__global__ __launch_bounds__(256, 3) void conv32_k(
    const float* __restrict__ in, const float* __restrict__ wgt,
    const float* __restrict__ bias, float* __restrict__ out, int cout) {
  constexpr int CIB = (CI >= 4) ? 4 : CI;
  constexpr int NST = CIB * 34 * 34;          // staged values per round
  constexpr int NLD = (NST + 255) / 256;
  constexpr int RS = 36;                      // padded LDS row stride
  constexpr int PS = 34 * RS;                 // plane stride (words)

  const int co0 = blockIdx.x * 8;
  const int tile = blockIdx.y;                // 0..48
  const int b = blockIdx.z;
  const int th0 = (tile / 7) * 32, tw0 = (tile % 7) * 32;
  const int tid = threadIdx.x;
  const int wv = tid >> 6, lane = tid & 63;
  const int ry = lane >> 3, cx = lane & 7;    // 8x8 lane grid, 4x4 px each

  __shared__ float sT[CIB * PS];

  // staging offsets (constant across rounds)
  int po[NLD];   // global offsets
  int so[NLD];   // LDS word offsets
  unsigned okm = 0;
#pragma unroll
  for (int j = 0; j < NLD; ++j) {
    int s = tid + 256 * j;
    int pl = s / (34 * 34), rem = s - pl * (34 * 34);
    int lr = rem / 34, lc = rem - lr * 34;
    int gh = th0 + lr - 1, gw = tw0 + lc - 1;
    bool ok = (s < NST) && gh >= 0 && gh < H_ && gw >= 0 && gw < W_;
    po[j] = ok ? (pl * HW + gh * W_ + gw) : 0;
    so[j] = (s < NST) ? (pl * PS + lr * RS + lc) : 0;
    if (ok) okm |= (1u << j);
  }

  const float* inB = in + (size_t)b * CI * HW;
  float stg[NLD];
#pragma unroll
  for (int j = 0; j < NLD; ++j) {
    float v = inB[po[j]];
    stg[j] = ((okm >> j) & 1) ? v : 0.f;
  }

  // weight base indices for this wave's two channels (clamped for NCOUT<2/wave)
  const int c0 = clampi(2 * wv + 0, 0, NCOUT - 1);
  const int c1 = clampi(2 * wv + 1, 0, NCOUT - 1);
  const float* wg0 = wgt + (size_t)(co0 + c0) * CI * 9;
  const float* wg1 = wgt + (size_t)(co0 + c1) * CI * 9;

  float acc[2][4][4];
  {
    float bv0 = bias[co0 + c0], bv1 = bias[co0 + c1];
#pragma unroll
    for (int r = 0; r < 4; ++r)
#pragma unroll
      for (int j = 0; j < 4; ++j) {
        acc[0][r][j] = bv0;
        acc[1][r][j] = bv1;
      }
  }

  for (int cb = 0; cb < CI; cb += CIB) {
    __syncthreads();
#pragma unroll
    for (int j = 0; j < NLD; ++j) {
      int s = tid + 256 * j;
      if (s < NST) sT[so[j]] = stg[j];
    }
    __syncthreads();
    if (cb + CIB < CI) {
      const float* inN = inB + (size_t)(cb + CIB) * HW;
#pragma unroll
      for (int j = 0; j < NLD; ++j) {
        float v = inN[po[j]];
        stg[j] = ((okm >> j) & 1) ? v : 0.f;
      }
    }
#pragma unroll
    for (int ci = 0; ci < CIB; ++ci) {
      // wave-uniform weights (scalar loads)
      const float* wp0 = wg0 + (size_t)(cb + ci) * 9;
      const float* wp1 = wg1 + (size_t)(cb + ci) * 9;
      float wa[2][9];
#pragma unroll
      for (int k = 0; k < 9; ++k) {
        wa[0][k] = wp0[k];
        wa[1][k] = wp1[k];
      }
      // 6x6 input window: 6 rows of b128+b64
      float iv[6][6];
#pragma unroll
      for (int dr = 0; dr < 6; ++dr) {
        const int base = ci * PS + (4 * ry + dr) * RS + 4 * cx;
        float4 a = *(const float4*)&sT[base];
        float2 e = *(const float2*)&sT[base + 4];
        iv[dr][0] = a.x; iv[dr][1] = a.y; iv[dr][2] = a.z; iv[dr][3] = a.w;
        iv[dr][4] = e.x; iv[dr][5] = e.y;
      }
#pragma unroll
      for (int c = 0; c < 2; ++c) {
#pragma unroll
        for (int r = 0; r < 4; ++r)
#pragma unroll
          for (int j = 0; j < 4; ++j) {
            acc[c][r][j] += iv[r + 0][j + 0] * wa[c][0] + iv[r + 0][j + 1] * wa[c][1] +
                            iv[r + 0][j + 2] * wa[c][2] + iv[r + 1][j + 0] * wa[c][3] +
                            iv[r + 1][j + 1] * wa[c][4] + iv[r + 1][j + 2] * wa[c][5] +
                            iv[r + 2][j + 0] * wa[c][6] + iv[r + 2][j + 1] * wa[c][7] +
                            iv[r + 2][j + 2] * wa[c][8];
          }
      }
    }
  }

#pragma unroll
  for (int c = 0; c < 2; ++c) {
    int cc = 2 * wv + c;
    if (cc < NCOUT) {
      float* ob = out + ((size_t)b * cout + co0 + cc) * HW;
#pragma unroll
      for (int r = 0; r < 4; ++r)
#pragma unroll
        for (int j = 0; j < 4; ++j) {
          int h = th0 + 4 * ry + r, w = tw0 + 4 * cx + j;
          float v = acc[c][r][j];
          if (RELU) v = fmaxf(v, 0.f);
          ob[h * W_ + w] = v;
        }
    }
  }
}

// ---------------------------------------------------------------------------
// Patch extraction: dst[b, n, c*100 + i*10 + j] = src[b, c, 5*q1+i, 5*q2+j]
// ---------------------------------------------------------------------------
__global__ __launch_bounds__(256) void patches_k(const float* __restrict__ src,
                                                 float* __restrict__ dst) {
  int i = blockIdx.x * 256 + threadIdx.x;
  constexpr int TOT = B_ * N_ * D_;
  if (i >= TOT) return;
  int d = i % D_;
  int n = (i / D_) % N_;
  int b = i / (D_ * N_);
  int c = d / 100;
  int rr = (d / 10) % 10;
  int cc = d % 10;
  int q1 = n / N2, q2 = n % N2;
  dst[i] = src[((size_t)(b * 8 + c) * H_ + q1 * 5 + rr) * W_ + q2 * 5 + cc];
}

// ---------------------------------------------------------------------------
// Per-(b,n): sq = ||pe||^2 ; lt = mean of 10x10 log_temp patch. 1 wave each.
// ---------------------------------------------------------------------------
__global__ __launch_bounds__(64) void ltsq_k(const float* __restrict__ pe,
                                             const float* __restrict__ ltmap,
                                             float* __restrict__ lt,
                                             float* __restrict__ sq) {
  int bn = blockIdx.x;
  int b = bn / N_, n = bn % N_;
  int lane = threadIdx.x;
  const float* p = pe + (size_t)bn * D_;
  float s = 0.f;
  for (int i = lane; i < D_; i += 64) {
    float v = p[i];
    s += v * v;
  }
#pragma unroll
  for (int off = 32; off > 0; off >>= 1) s += __shfl_xor(s, off);
  int q1 = n / N2, q2 = n % N2;
  const float* lm = ltmap + (size_t)b * HW;
  float t = 0.f;
  for (int i = lane; i < 100; i += 64)
    t += lm[(q1 * 5 + i / 10) * W_ + q2 * 5 + i % 10];
#pragma unroll
  for (int off = 32; off > 0; off >>= 1) t += __shfl_xor(t, off);
  if (lane == 0) {
    sq[bn] = s;
    lt[bn] = t * 0.01f;
  }
}

// ---------------------------------------------------------------------------
// attn stage 1: one wave per (b,n). Query row in registers, 49 dots,
// K softmax rounds in-wave, write Wk[b,n,m,k].
// ---------------------------------------------------------------------------
__global__ __launch_bounds__(64) void attn_w_k(const float* __restrict__ pe,
                                               const float* __restrict__ lt,
                                               const float* __restrict__ sq,
                                               float* __restrict__ wk) {
  const int n = swiz_n(blockIdx.x);
  if (n >= N_) return;
  const int b = blockIdx.y;
  const int lane = threadIdx.x;
  const int q1 = n / N2, q2 = n % N2;

  const float* peB = pe + (size_t)b * N_ * D_;
  const float* qrow = peB + (size_t)n * D_;
  float q[13];
#pragma unroll
  for (int t = 0; t < 13; ++t) {
    int s = t * 64 + lane;
    q[t] = (s < D_) ? qrow[s] : 0.f;
  }

  __shared__ float sG[M_];

  for (int o1 = 0; o1 < 7; ++o1) {
    int c1 = clampi(q1 + o1 - 3, 0, N1 - 1);
    const float* rowb = peB + (size_t)(c1 * N2) * D_;
#pragma unroll
    for (int o2 = 0; o2 < 7; ++o2) {
      int c2 = clampi(q2 + o2 - 3, 0, N2 - 1);
      const float* crow = rowb + (size_t)c2 * D_;
      float a = 0.f;
#pragma unroll
      for (int t = 0; t < 13; ++t) {
        float v;
        if (t < 12) v = crow[t * 64 + lane];
        else v = (lane < 32) ? crow[768 + lane] : 0.f;
        a += q[t] * v;
      }
#pragma unroll
      for (int off = 32; off > 0; off >>= 1) a += __shfl_xor(a, off);
      if (lane == 0) sG[o1 * 7 + o2] = a;
    }
  }
  __syncthreads();

  const float sqn = sq[b * N_ + n];
  const float itemp = expf(-lt[b * N_ + n]);
  float cur = -INFINITY;
  if (lane < M_) {
    int c1 = clampi(q1 + lane / 7 - 3, 0, N1 - 1);
    int c2 = clampi(q2 + lane % 7 - 3, 0, N2 - 1);
    int cn = c1 * N2 + c2;
    float Dv = -(sqn + sq[b * N_ + cn] - 2.f * sG[lane]);
    cur = (cn == n) ? -1e9f : Dv * itemp;
  }
  float* wrow = wk + (size_t)(b * N_ + n) * (M_ * K_);
#pragma unroll
  for (int k = 0; k < K_; ++k) {
    float mx = cur;
#pragma unroll
    for (int off = 32; off > 0; off >>= 1) mx = fmaxf(mx, __shfl_xor(mx, off));
    float e = (lane < M_) ? expf(cur - mx) : 0.f;
    float ssum = e;
#pragma unroll
    for (int off = 32; off > 0; off >>= 1) ssum += __shfl_xor(ssum, off);
    float w = e / ssum;
    if (lane < M_) wrow[lane * K_ + k] = w;
    cur += log1pf(-fminf(w, 1.f - 1e-6f));
  }
}

// ---------------------------------------------------------------------------
// attn stage 2: one wave per (b, n, d-slice of 64). Weights via scalar loads
// (block-uniform), 7 accumulators, 49 independent coalesced y loads.
// ---------------------------------------------------------------------------
__global__ __launch_bounds__(64) void attn_pv_k(const float* __restrict__ yp,
                                                const float* __restrict__ wk,
                                                float* __restrict__ nb) {
  const int n = swiz_n(blockIdx.x);
  if (n >= N_) return;
  const int b = blockIdx.z;
  const int d = blockIdx.y * 64 + threadIdx.x;
  const bool valid = d < D_;
  const int q1 = n / N2, q2 = n % N2;

  const float* ypB = yp + (size_t)b * N_ * D_;
  const float* wrow = wk + (size_t)(b * N_ + n) * (M_ * K_);

  float acc[K_];
#pragma unroll
  for (int k = 0; k < K_; ++k) acc[k] = 0.f;

#pragma unroll
  for (int o1 = 0; o1 < 7; ++o1) {
    int c1 = clampi(q1 + o1 - 3, 0, N1 - 1);
#pragma unroll
    for (int o2 = 0; o2 < 7; ++o2) {
      int c2 = clampi(q2 + o2 - 3, 0, N2 - 1);
      int cn = c1 * N2 + c2;
      float y = valid ? ypB[(size_t)cn * D_ + d] : 0.f;
      const int m = o1 * 7 + o2;
#pragma unroll
      for (int k = 0; k < K_; ++k) acc[k] += wrow[m * K_ + k] * y;
    }
  }
  if (valid) {
#pragma unroll
    for (int k = 0; k < K_; ++k)
      nb[(((size_t)k * B_ + b) * N_ + n) * D_ + d] = acc[k];
  }
}

// ---------------------------------------------------------------------------
// Fused output: channels 0..7 copy x; channels 8..63 fold-gather from nb.
// ---------------------------------------------------------------------------
__global__ __launch_bounds__(256) void foldcopy_k(const float* __restrict__ x,
                                                  const float* __restrict__ nb,
                                                  float* __restrict__ out) {
  int i = blockIdx.x * 256 + threadIdx.x;
  constexpr int CT = CIN * (K_ + 1);  // 64
  constexpr int TOT = B_ * CT * HW;
  if (i >= TOT) return;
  int w = i % W_;
  int h = (i / W_) % H_;
  int c64 = (i / HW) % CT;
  int b = i / (HW * CT);
  if (c64 < CIN) {
    out[i] = x[((size_t)b * CIN + c64) * HW + h * W_ + w];
    return;
  }
  int k = (c64 - CIN) >> 3, c = (c64 - CIN) & 7;
  int q1lo = max(0, (h - 5) / 5), q1hi = min(N1 - 1, h / 5);
  int q2lo = max(0, (w - 5) / 5), q2hi = min(N2 - 1, w / 5);
  float val = 0.f;
  int cnt = 0;
  for (int q1 = q1lo; q1 <= q1hi; ++q1)
    for (int q2 = q2lo; q2 <= q2hi; ++q2) {
      int i0 = h - 5 * q1, j0 = w - 5 * q2;
      int nn = q1 * N2 + q2;
      val += nb[(((size_t)k * B_ + b) * N_ + nn) * D_ + c * 100 + i0 * 10 + j0];
      ++cnt;
    }
  out[i] = (cnt > 0) ? val / (float)cnt : 0.f;
}

extern "C" void kernel_launch(void* const* d_in, const int* in_sizes, int n_in,
                              void* d_out, int out_size, void* d_ws,
                              size_t ws_size, hipStream_t stream) {
  const float* x   = (const float*)d_in[0];
  const float* w1e = (const float*)d_in[1];
  const float* b1e = (const float*)d_in[2];
  const float* w2e = (const float*)d_in[3];
  const float* b2e = (const float*)d_in[4];
  const float* w3e = (const float*)d_in[5];
  const float* b3e = (const float*)d_in[6];
  const float* w1t = (const float*)d_in[7];
  const float* b1t = (const float*)d_in[8];
  const float* w2t = (const float*)d_in[9];
  const float* b2t = (const float*)d_in[10];
  const float* w3t = (const float*)d_in[11];
  const float* b3t = (const float*)d_in[12];

  float* ws  = (float*)d_ws;
  float* out = (float*)d_out;

  float* h1e = ws + OFF_H1E;
  float* h1t = ws + OFF_H1T;
  float* h2e = ws + OFF_H2E;
  float* h2t = ws + OFF_H2T;
  float* wkb = ws + OFF_WK;
  float* nb  = ws + OFF_NB;
  float* xe  = ws + OFF_XE;
  float* ltm = ws + OFF_LTM;
  float* pe  = ws + OFF_PE;
  float* yp  = ws + OFF_YP;
  float* lt  = ws + OFF_LT;
  float* sqv = ws + OFF_SQ;

  // conv1 (8 -> 64, relu): grid (8 cogs, 49 tiles, B)
  conv32_k<CIN, 8, true><<<dim3(8, 49, B_), 256, 0, stream>>>(x, w1e, b1e, h1e, F_);
  conv32_k<CIN, 8, true><<<dim3(8, 49, B_), 256, 0, stream>>>(x, w1t, b1t, h1t, F_);
  // conv2 (64 -> 64, relu)
  conv32_k<F_, 8, true><<<dim3(8, 49, B_), 256, 0, stream>>>(h1e, w2e, b2e, h2e, F_);
  conv32_k<F_, 8, true><<<dim3(8, 49, B_), 256, 0, stream>>>(h1t, w2t, b2t, h2t, F_);
  // conv3 (64 -> 8 / 64 -> 1)
  conv32_k<F_, 8, false><<<dim3(1, 49, B_), 256, 0, stream>>>(h2e, w3e, b3e, xe, E_);
  conv32_k<F_, 1, false><<<dim3(1, 49, B_), 256, 0, stream>>>(h2t, w3t, b3t, ltm, 1);
  // patches
  constexpr int PT = B_ * N_ * D_;
  patches_k<<<(PT + 255) / 256, 256, 0, stream>>>(xe, pe);
  patches_k<<<(PT + 255) / 256, 256, 0, stream>>>(x, yp);
  // per-patch norms + log-temp means
  ltsq_k<<<B_ * N_, 64, 0, stream>>>(pe, ltm, lt, sqv);
  // attention stage 1: weights
  attn_w_k<<<dim3(NSW, B_), 64, 0, stream>>>(pe, lt, sqv, wkb);
  // attention stage 2: weighted neighbor sums (d split into 13 slices)
  attn_pv_k<<<dim3(NSW, 13, B_), 64, 0, stream>>>(yp, wkb, nb);
  // fused fold + x passthrough
  constexpr int FT = B_ * CIN * (K_ + 1) * HW;
  foldcopy_k<<<(FT + 255) / 256, 256, 0, stream>>>(x, nb, out);
}

// Round 5
// 1248.890 us; speedup vs baseline: 2.5959x; 2.5959x over previous
//
#include <hip/hip_runtime.h>
#include <math.h>

namespace {
constexpr int B_ = 2, CIN = 8, H_ = 224, W_ = 224;
constexpr int K_ = 7;
constexpr int F_ = 64, E_ = 8;
constexpr int N1 = 43, N2 = 43, N_ = N1 * N2;   // 1849
constexpr int M_ = 49;                           // candidates per query
constexpr int D_ = 800;                          // patch dim (C*P*P)
constexpr int HW = H_ * W_;
constexpr int NSW = 1856;                        // swizzled grid for n (8*232)

// workspace layout (floats).
constexpr size_t FHW = (size_t)B_ * F_ * HW;     // 6,422,528
constexpr size_t OFF_H1E = 0;
constexpr size_t OFF_H1T = OFF_H1E + FHW;
constexpr size_t OFF_H2E = OFF_H1T + FHW;
constexpr size_t OFF_H2T = OFF_H2E + FHW;
constexpr size_t OFF_WK  = 0;                                  // B*N*343
constexpr size_t OFF_NB  = 1280000;                            // > Wk end
constexpr size_t OFF_XE  = OFF_H2T + FHW;
constexpr size_t OFF_LTM = OFF_XE + (size_t)B_ * E_ * HW;
constexpr size_t OFF_PE  = OFF_LTM + (size_t)B_ * HW;
constexpr size_t OFF_YP  = OFF_PE + (size_t)B_ * N_ * D_;
constexpr size_t OFF_LT  = OFF_YP + (size_t)B_ * N_ * D_;
constexpr size_t OFF_SQ  = OFF_LT + (size_t)B_ * N_;

__device__ __forceinline__ int clampi(int v, int lo, int hi) {
  return min(max(v, lo), hi);
}
__device__ __forceinline__ int swiz_n(int xr) { return (xr & 7) * 232 + (xr >> 3); }
} // namespace

// ---------------------------------------------------------------------------
// 3x3 SAME conv, NCHW, 32x32 tile, 256 threads. Thread (ty=tid>>5, tx=tid&31)
// owns 4 rows x 1 col (rows 4ty..4ty+3, col tx): stride-1 LDS reads -> 2-way
// bank aliasing only (free; R3 measured 0 conflicts). Each thread computes
// NCOUT output channels (acc[NCOUT][4]). Weights are wave-uniform -> scalar
// loads from global (K$), loaded per-cout inside the unrolled loop (no LDS
// broadcast traffic, no SGPR overflow). Input planes staged CIB=4/round with
// register prefetch of the next round. Default launch bounds -> no spills.
// ---------------------------------------------------------------------------
template <int CI, int NCOUT, bool RELU>
__global__ __launch_bounds__(256) void conv32_k(
    const float* __restrict__ in, const float* __restrict__ wgt,
    const float* __restrict__ bias, float* __restrict__ out, int cout) {
  constexpr int CIB = (CI >= 4) ? 4 : CI;
  constexpr int NST = CIB * 34 * 34;          // staged values per round
  constexpr int NLD = (NST + 255) / 256;

  const int co0 = blockIdx.x * 8;             // cout-group base (8-stride)
  const int tile = blockIdx.y;                // 0..48
  const int b = blockIdx.z;
  const int th0 = (tile / 7) * 32, tw0 = (tile % 7) * 32;
  const int tid = threadIdx.x;
  const int tx = tid & 31, ty = tid >> 5;     // ty 0..7, rows 4*ty..4*ty+3

  __shared__ float sT[CIB][34 * 34];

  // staging offsets (constant across rounds)
  int po[NLD];
  unsigned okm = 0;
#pragma unroll
  for (int j = 0; j < NLD; ++j) {
    int s = tid + 256 * j;
    int pl = s / (34 * 34), rem = s - pl * (34 * 34);
    int lr = rem / 34, lc = rem - lr * 34;
    int gh = th0 + lr - 1, gw = tw0 + lc - 1;
    bool ok = (s < NST) && gh >= 0 && gh < H_ && gw >= 0 && gw < W_;
    po[j] = ok ? (pl * HW + gh * W_ + gw) : 0;
    if (ok) okm |= (1u << j);
  }

  const float* inB = in + (size_t)b * CI * HW;
  float stg[NLD];
#pragma unroll
  for (int j = 0; j < NLD; ++j) {
    float v = inB[po[j]];
    stg[j] = ((okm >> j) & 1) ? v : 0.f;
  }

  float acc[NCOUT][4];
#pragma unroll
  for (int c = 0; c < NCOUT; ++c) {
    float bv = bias[co0 + c];
#pragma unroll
    for (int r = 0; r < 4; ++r) acc[c][r] = bv;
  }

  const float* wgB = wgt + (size_t)co0 * CI * 9;

  for (int cb = 0; cb < CI; cb += CIB) {
    __syncthreads();
#pragma unroll
    for (int j = 0; j < NLD; ++j) {
      int s = tid + 256 * j;
      if (s < NST) ((float*)sT)[s] = stg[j];
    }
    __syncthreads();
    if (cb + CIB < CI) {
      const float* inN = inB + (size_t)(cb + CIB) * HW;
#pragma unroll
      for (int j = 0; j < NLD; ++j) {
        float v = inN[po[j]];
        stg[j] = ((okm >> j) & 1) ? v : 0.f;
      }
    }
#pragma unroll
    for (int ci = 0; ci < CIB; ++ci) {
      // 6 rows x 3 cols of input, stride-1 in tx (conflict-free)
      float iv[6][3];
#pragma unroll
      for (int r = 0; r < 6; ++r)
#pragma unroll
        for (int s2 = 0; s2 < 3; ++s2)
          iv[r][s2] = sT[ci][(4 * ty + r) * 34 + tx + s2];
      const float* wci = wgB + (size_t)(cb + ci) * 9;
#pragma unroll
      for (int c = 0; c < NCOUT; ++c) {
        const float* wp = wci + (size_t)c * CI * 9;  // wave-uniform -> s_load
        float w0 = wp[0], w1 = wp[1], w2 = wp[2], w3 = wp[3], w4 = wp[4];
        float w5 = wp[5], w6 = wp[6], w7 = wp[7], w8 = wp[8];
#pragma unroll
        for (int dy = 0; dy < 4; ++dy) {
          acc[c][dy] += iv[dy + 0][0] * w0 + iv[dy + 0][1] * w1 +
                        iv[dy + 0][2] * w2 + iv[dy + 1][0] * w3 +
                        iv[dy + 1][1] * w4 + iv[dy + 1][2] * w5 +
                        iv[dy + 2][0] * w6 + iv[dy + 2][1] * w7 +
                        iv[dy + 2][2] * w8;
        }
      }
    }
  }

#pragma unroll
  for (int c = 0; c < NCOUT; ++c) {
    float* ob = out + ((size_t)b * cout + co0 + c) * HW;
#pragma unroll
    for (int dy = 0; dy < 4; ++dy) {
      int h = th0 + 4 * ty + dy, w = tw0 + tx;
      float v = acc[c][dy];
      if (RELU) v = fmaxf(v, 0.f);
      ob[h * W_ + w] = v;
    }
  }
}

// ---------------------------------------------------------------------------
// Patch extraction: dst[b, n, c*100 + i*10 + j] = src[b, c, 5*q1+i, 5*q2+j]
// ---------------------------------------------------------------------------
__global__ __launch_bounds__(256) void patches_k(const float* __restrict__ src,
                                                 float* __restrict__ dst) {
  int i = blockIdx.x * 256 + threadIdx.x;
  constexpr int TOT = B_ * N_ * D_;
  if (i >= TOT) return;
  int d = i % D_;
  int n = (i / D_) % N_;
  int b = i / (D_ * N_);
  int c = d / 100;
  int rr = (d / 10) % 10;
  int cc = d % 10;
  int q1 = n / N2, q2 = n % N2;
  dst[i] = src[((size_t)(b * 8 + c) * H_ + q1 * 5 + rr) * W_ + q2 * 5 + cc];
}

// ---------------------------------------------------------------------------
// Per-(b,n): sq = ||pe||^2 ; lt = mean of 10x10 log_temp patch. 1 wave each.
// ---------------------------------------------------------------------------
__global__ __launch_bounds__(64) void ltsq_k(const float* __restrict__ pe,
                                             const float* __restrict__ ltmap,
                                             float* __restrict__ lt,
                                             float* __restrict__ sq) {
  int bn = blockIdx.x;
  int b = bn / N_, n = bn % N_;
  int lane = threadIdx.x;
  const float* p = pe + (size_t)bn * D_;
  float s = 0.f;
  for (int i = lane; i < D_; i += 64) {
    float v = p[i];
    s += v * v;
  }
#pragma unroll
  for (int off = 32; off > 0; off >>= 1) s += __shfl_xor(s, off);
  int q1 = n / N2, q2 = n % N2;
  const float* lm = ltmap + (size_t)b * HW;
  float t = 0.f;
  for (int i = lane; i < 100; i += 64)
    t += lm[(q1 * 5 + i / 10) * W_ + q2 * 5 + i % 10];
#pragma unroll
  for (int off = 32; off > 0; off >>= 1) t += __shfl_xor(t, off);
  if (lane == 0) {
    sq[bn] = s;
    lt[bn] = t * 0.01f;
  }
}

// ---------------------------------------------------------------------------
// attn stage 1: one wave per (b,n). Query row in registers, 49 dots,
// K softmax rounds in-wave, write Wk[b,n,m,k].
// ---------------------------------------------------------------------------
__global__ __launch_bounds__(64) void attn_w_k(const float* __restrict__ pe,
                                               const float* __restrict__ lt,
                                               const float* __restrict__ sq,
                                               float* __restrict__ wk) {
  const int n = swiz_n(blockIdx.x);
  if (n >= N_) return;
  const int b = blockIdx.y;
  const int lane = threadIdx.x;
  const int q1 = n / N2, q2 = n % N2;

  const float* peB = pe + (size_t)b * N_ * D_;
  const float* qrow = peB + (size_t)n * D_;
  float q[13];
#pragma unroll
  for (int t = 0; t < 13; ++t) {
    int s = t * 64 + lane;
    q[t] = (s < D_) ? qrow[s] : 0.f;
  }

  __shared__ float sG[M_];

  for (int o1 = 0; o1 < 7; ++o1) {
    int c1 = clampi(q1 + o1 - 3, 0, N1 - 1);
    const float* rowb = peB + (size_t)(c1 * N2) * D_;
#pragma unroll
    for (int o2 = 0; o2 < 7; ++o2) {
      int c2 = clampi(q2 + o2 - 3, 0, N2 - 1);
      const float* crow = rowb + (size_t)c2 * D_;
      float a = 0.f;
#pragma unroll
      for (int t = 0; t < 13; ++t) {
        float v;
        if (t < 12) v = crow[t * 64 + lane];
        else v = (lane < 32) ? crow[768 + lane] : 0.f;
        a += q[t] * v;
      }
#pragma unroll
      for (int off = 32; off > 0; off >>= 1) a += __shfl_xor(a, off);
      if (lane == 0) sG[o1 * 7 + o2] = a;
    }
  }
  __syncthreads();

  const float sqn = sq[b * N_ + n];
  const float itemp = expf(-lt[b * N_ + n]);
  float cur = -INFINITY;
  if (lane < M_) {
    int c1 = clampi(q1 + lane / 7 - 3, 0, N1 - 1);
    int c2 = clampi(q2 + lane % 7 - 3, 0, N2 - 1);
    int cn = c1 * N2 + c2;
    float Dv = -(sqn + sq[b * N_ + cn] - 2.f * sG[lane]);
    cur = (cn == n) ? -1e9f : Dv * itemp;
  }
  float* wrow = wk + (size_t)(b * N_ + n) * (M_ * K_);
#pragma unroll
  for (int k = 0; k < K_; ++k) {
    float mx = cur;
#pragma unroll
    for (int off = 32; off > 0; off >>= 1) mx = fmaxf(mx, __shfl_xor(mx, off));
    float e = (lane < M_) ? expf(cur - mx) : 0.f;
    float ssum = e;
#pragma unroll
    for (int off = 32; off > 0; off >>= 1) ssum += __shfl_xor(ssum, off);
    float w = e / ssum;
    if (lane < M_) wrow[lane * K_ + k] = w;
    cur += log1pf(-fminf(w, 1.f - 1e-6f));
  }
}

// ---------------------------------------------------------------------------
// attn stage 2: one wave per (b, n, d-slice of 64). Weights via scalar loads
// (block-uniform), 7 accumulators, 49 independent coalesced y loads.
// ---------------------------------------------------------------------------
__global__ __launch_bounds__(64) void attn_pv_k(const float* __restrict__ yp,
                                                const float* __restrict__ wk,
                                                float* __restrict__ nb) {
  const int n = swiz_n(blockIdx.x);
  if (n >= N_) return;
  const int b = blockIdx.z;
  const int d = blockIdx.y * 64 + threadIdx.x;
  const bool valid = d < D_;
  const int q1 = n / N2, q2 = n % N2;

  const float* ypB = yp + (size_t)b * N_ * D_;
  const float* wrow = wk + (size_t)(b * N_ + n) * (M_ * K_);

  float acc[K_];
#pragma unroll
  for (int k = 0; k < K_; ++k) acc[k] = 0.f;

#pragma unroll
  for (int o1 = 0; o1 < 7; ++o1) {
    int c1 = clampi(q1 + o1 - 3, 0, N1 - 1);
#pragma unroll
    for (int o2 = 0; o2 < 7; ++o2) {
      int c2 = clampi(q2 + o2 - 3, 0, N2 - 1);
      int cn = c1 * N2 + c2;
      float y = valid ? ypB[(size_t)cn * D_ + d] : 0.f;
      const int m = o1 * 7 + o2;
#pragma unroll
      for (int k = 0; k < K_; ++k) acc[k] += wrow[m * K_ + k] * y;
    }
  }
  if (valid) {
#pragma unroll
    for (int k = 0; k < K_; ++k)
      nb[(((size_t)k * B_ + b) * N_ + n) * D_ + d] = acc[k];
  }
}

// ---------------------------------------------------------------------------
// Fused output: channels 0..7 copy x; channels 8..63 fold-gather from nb.
// ---------------------------------------------------------------------------
__global__ __launch_bounds__(256) void foldcopy_k(const float* __restrict__ x,
                                                  const float* __restrict__ nb,
                                                  float* __restrict__ out) {
  int i = blockIdx.x * 256 + threadIdx.x;
  constexpr int CT = CIN * (K_ + 1);  // 64
  constexpr int TOT = B_ * CT * HW;
  if (i >= TOT) return;
  int w = i % W_;
  int h = (i / W_) % H_;
  int c64 = (i / HW) % CT;
  int b = i / (HW * CT);
  if (c64 < CIN) {
    out[i] = x[((size_t)b * CIN + c64) * HW + h * W_ + w];
    return;
  }
  int k = (c64 - CIN) >> 3, c = (c64 - CIN) & 7;
  int q1lo = max(0, (h - 5) / 5), q1hi = min(N1 - 1, h / 5);
  int q2lo = max(0, (w - 5) / 5), q2hi = min(N2 - 1, w / 5);
  float val = 0.f;
  int cnt = 0;
  for (int q1 = q1lo; q1 <= q1hi; ++q1)
    for (int q2 = q2lo; q2 <= q2hi; ++q2) {
      int i0 = h - 5 * q1, j0 = w - 5 * q2;
      int nn = q1 * N2 + q2;
      val += nb[(((size_t)k * B_ + b) * N_ + nn) * D_ + c * 100 + i0 * 10 + j0];
      ++cnt;
    }
  out[i] = (cnt > 0) ? val / (float)cnt : 0.f;
}

extern "C" void kernel_launch(void* const* d_in, const int* in_sizes, int n_in,
                              void* d_out, int out_size, void* d_ws,
                              size_t ws_size, hipStream_t stream) {
  const float* x   = (const float*)d_in[0];
  const float* w1e = (const float*)d_in[1];
  const float* b1e = (const float*)d_in[2];
  const float* w2e = (const float*)d_in[3];
  const float* b2e = (const float*)d_in[4];
  const float* w3e = (const float*)d_in[5];
  const float* b3e = (const float*)d_in[6];
  const float* w1t = (const float*)d_in[7];
  const float* b1t = (const float*)d_in[8];
  const float* w2t = (const float*)d_in[9];
  const float* b2t = (const float*)d_in[10];
  const float* w3t = (const float*)d_in[11];
  const float* b3t = (const float*)d_in[12];

  float* ws  = (float*)d_ws;
  float* out = (float*)d_out;

  float* h1e = ws + OFF_H1E;
  float* h1t = ws + OFF_H1T;
  float* h2e = ws + OFF_H2E;
  float* h2t = ws + OFF_H2T;
  float* wkb = ws + OFF_WK;
  float* nb  = ws + OFF_NB;
  float* xe  = ws + OFF_XE;
  float* ltm = ws + OFF_LTM;
  float* pe  = ws + OFF_PE;
  float* yp  = ws + OFF_YP;
  float* lt  = ws + OFF_LT;
  float* sqv = ws + OFF_SQ;

  // conv1 (8 -> 64, relu): grid (8 cogs, 49 tiles, B)
  conv32_k<CIN, 8, true><<<dim3(8, 49, B_), 256, 0, stream>>>(x, w1e, b1e, h1e, F_);
  conv32_k<CIN, 8, true><<<dim3(8, 49, B_), 256, 0, stream>>>(x, w1t, b1t, h1t, F_);
  // conv2 (64 -> 64, relu)
  conv32_k<F_, 8, true><<<dim3(8, 49, B_), 256, 0, stream>>>(h1e, w2e, b2e, h2e, F_);
  conv32_k<F_, 8, true><<<dim3(8, 49, B_), 256, 0, stream>>>(h1t, w2t, b2t, h2t, F_);
  // conv3 (64 -> 8 / 64 -> 1)
  conv32_k<F_, 8, false><<<dim3(1, 49, B_), 256, 0, stream>>>(h2e, w3e, b3e, xe, E_);
  conv32_k<F_, 1, false><<<dim3(1, 49, B_), 256, 0, stream>>>(h2t, w3t, b3t, ltm, 1);
  // patches
  constexpr int PT = B_ * N_ * D_;
  patches_k<<<(PT + 255) / 256, 256, 0, stream>>>(xe, pe);
  patches_k<<<(PT + 255) / 256, 256, 0, stream>>>(x, yp);
  // per-patch norms + log-temp means
  ltsq_k<<<B_ * N_, 64, 0, stream>>>(pe, ltm, lt, sqv);
  // attention stage 1: weights
  attn_w_k<<<dim3(NSW, B_), 64, 0, stream>>>(pe, lt, sqv, wkb);
  // attention stage 2: weighted neighbor sums (d split into 13 slices)
  attn_pv_k<<<dim3(NSW, 13, B_), 64, 0, stream>>>(yp, wkb, nb);
  // fused fold + x passthrough
  constexpr int FT = B_ * CIN * (K_ + 1) * HW;
  foldcopy_k<<<(FT + 255) / 256, 256, 0, stream>>>(x, nb, out);
}

// Round 6
// 585.445 us; speedup vs baseline: 5.5378x; 2.1332x over previous
//
#include <hip/hip_runtime.h>
#include <math.h>

namespace {
constexpr int B_ = 2, CIN = 8, H_ = 224, W_ = 224;
constexpr int K_ = 7;
constexpr int F_ = 64, E_ = 8;
constexpr int N1 = 43, N2 = 43, N_ = N1 * N2;   // 1849
constexpr int M_ = 49;                           // candidates per query
constexpr int D_ = 800;                          // patch dim (C*P*P)
constexpr int HW = H_ * W_;
constexpr int NSW = 1856;                        // swizzled grid for n (8*232)

// workspace layout (floats).
constexpr size_t FHW = (size_t)B_ * F_ * HW;     // 6,422,528
constexpr size_t OFF_H1E = 0;                    // channels-last [b][h][w][64]
constexpr size_t OFF_H1T = OFF_H1E + FHW;
constexpr size_t OFF_H2E = OFF_H1T + FHW;        // NCHW
constexpr size_t OFF_H2T = OFF_H2E + FHW;
constexpr size_t OFF_WK  = 0;                                  // B*N*343
constexpr size_t OFF_NB  = 1280000;                            // > Wk end
constexpr size_t OFF_XE  = OFF_H2T + FHW;
constexpr size_t OFF_LTM = OFF_XE + (size_t)B_ * E_ * HW;
constexpr size_t OFF_PE  = OFF_LTM + (size_t)B_ * HW;
constexpr size_t OFF_YP  = OFF_PE + (size_t)B_ * N_ * D_;
constexpr size_t OFF_LT  = OFF_YP + (size_t)B_ * N_ * D_;
constexpr size_t OFF_SQ  = OFF_LT + (size_t)B_ * N_;

__device__ __forceinline__ int clampi(int v, int lo, int hi) {
  return min(max(v, lo), hi);
}
__device__ __forceinline__ int swiz_n(int xr) { return (xr & 7) * 232 + (xr >> 3); }

typedef __attribute__((ext_vector_type(8))) short short8;
typedef __attribute__((ext_vector_type(4))) float float4v;
} // namespace

// ---------------------------------------------------------------------------
// conv1: R3-proven VALU conv (weights in LDS, stride-1 tx -> 0 conflicts),
// 32x32 tile, 8 couts/block, 4 rows/thread. CL=true stores channels-last
// [b][h][w][64] for the MFMA conv2's coalesced staging.
// ---------------------------------------------------------------------------
template <int CI, int COG, bool RELU, bool CL>
__global__ __launch_bounds__(256) void conv32_k(
    const float* __restrict__ in, const float* __restrict__ wgt,
    const float* __restrict__ bias, float* __restrict__ out, int cout) {
  constexpr int CIB = (CI >= 4) ? 4 : CI;
  constexpr int TP = 34;
  constexpr int NST = CIB * TP * TP;
  constexpr int NLD = (NST + 255) / 256;

  const int cog = blockIdx.x;
  const int tile = blockIdx.y;
  const int b = blockIdx.z;
  const int co0 = cog * COG;
  const int th0 = (tile / 7) * 32, tw0 = (tile % 7) * 32;
  const int tid = threadIdx.x;
  const int tx = tid & 31, ty = tid >> 5;

  __shared__ float sW[COG * CI * 12];
  __shared__ float sT[CIB][TP * TP];

  for (int s = tid; s < COG * CI * 12; s += 256) {
    int c = s / (CI * 12);
    int rem = s - c * (CI * 12);
    int ci = rem / 12, r = rem - ci * 12;
    sW[s] = (r < 9) ? wgt[((size_t)(co0 + c) * CI + ci) * 9 + r] : 0.f;
  }

  int po[NLD];
  unsigned okm = 0;
#pragma unroll
  for (int j = 0; j < NLD; ++j) {
    int s = tid + 256 * j;
    int pl = s / (TP * TP), rem = s - pl * (TP * TP);
    int lr = rem / TP, lc = rem - lr * TP;
    int gh = th0 + lr - 1, gw = tw0 + lc - 1;
    bool ok = (s < NST) && gh >= 0 && gh < H_ && gw >= 0 && gw < W_;
    po[j] = ok ? (pl * HW + gh * W_ + gw) : 0;
    if (ok) okm |= (1u << j);
  }

  const float* inB = in + (size_t)b * CI * HW;
  float stg[NLD];
#pragma unroll
  for (int j = 0; j < NLD; ++j) {
    float v = inB[po[j]];
    stg[j] = ((okm >> j) & 1) ? v : 0.f;
  }

  float acc[COG][4];
#pragma unroll
  for (int c = 0; c < COG; ++c) {
    float bv = bias[co0 + c];
#pragma unroll
    for (int r = 0; r < 4; ++r) acc[c][r] = bv;
  }

  for (int cb = 0; cb < CI; cb += CIB) {
    __syncthreads();
#pragma unroll
    for (int j = 0; j < NLD; ++j) {
      int s = tid + 256 * j;
      if (s < NST) ((float*)sT)[s] = stg[j];
    }
    __syncthreads();
    if (cb + CIB < CI) {
      const float* inN = inB + (size_t)(cb + CIB) * HW;
#pragma unroll
      for (int j = 0; j < NLD; ++j) {
        float v = inN[po[j]];
        stg[j] = ((okm >> j) & 1) ? v : 0.f;
      }
    }
#pragma unroll
    for (int ci = 0; ci < CIB; ++ci) {
      float iv[6][3];
#pragma unroll
      for (int r = 0; r < 6; ++r)
#pragma unroll
        for (int s2 = 0; s2 < 3; ++s2)
          iv[r][s2] = sT[ci][(4 * ty + r) * 34 + tx + s2];
#pragma unroll
      for (int c = 0; c < COG; ++c) {
        const float4* wp = (const float4*)&sW[(c * CI + cb + ci) * 12];
        float4 wa = wp[0], wb = wp[1], wc = wp[2];
#pragma unroll
        for (int dy = 0; dy < 4; ++dy) {
          acc[c][dy] += iv[dy + 0][0] * wa.x + iv[dy + 0][1] * wa.y +
                        iv[dy + 0][2] * wa.z + iv[dy + 1][0] * wa.w +
                        iv[dy + 1][1] * wb.x + iv[dy + 1][2] * wb.y +
                        iv[dy + 2][0] * wb.z + iv[dy + 2][1] * wb.w +
                        iv[dy + 2][2] * wc.x;
        }
      }
    }
  }

#pragma unroll
  for (int c = 0; c < COG; ++c)
#pragma unroll
    for (int dy = 0; dy < 4; ++dy) {
      int h = th0 + 4 * ty + dy, w = tw0 + tx;
      float v = acc[c][dy];
      if (RELU) v = fmaxf(v, 0.f);
      if (CL)
        out[(((size_t)b * H_ + h) * W_ + w) * 64 + co0 + c] = v;
      else
        out[((size_t)b * cout + co0 + c) * HW + h * W_ + w] = v;
    }
}

// ---------------------------------------------------------------------------
// conv2 (64->64, relu) via MFMA bf16 with 3-term hi/lo split (~fp32 accurate).
// 9 shifted GEMMs: C[co,px] += W[co,ci](ky,kx) * I[ci, px shifted].
// Block: 256 thr (4 waves), 16x16 px tile, wave w owns couts 16w..16w+15.
// Input (channels-last) staged to LDS [18x18 sp][72: hi ci0-31 | lo | pad],
// row stride 144B == 4 mod 32 words -> b128 fragment reads conflict-free.
// A-fragments gathered from global fp32 weights per (shift, kstep).
// blockIdx.z: bit0 = batch, bit1 = branch (e/t merged for load balance).
// ---------------------------------------------------------------------------
__global__ __launch_bounds__(256) void conv2_mfma_k(
    const float* __restrict__ in_e, const float* __restrict__ in_t,
    const float* __restrict__ w_e, const float* __restrict__ w_t,
    const float* __restrict__ b_e, const float* __restrict__ b_t,
    float* __restrict__ out_e, float* __restrict__ out_t) {
  const int tile = blockIdx.x;
  const int b = blockIdx.z & 1;
  const int br = blockIdx.z >> 1;
  const float* in = br ? in_t : in_e;
  const float* wgt = br ? w_t : w_e;
  const float* bias = br ? b_t : b_e;
  float* out = br ? out_t : out_e;

  const int th0 = (tile / 14) * 16, tw0 = (tile % 14) * 16;
  const int tid = threadIdx.x;
  const int wv = tid >> 6, lane = tid & 63;
  const int q = lane >> 4, n = lane & 15;

  __shared__ unsigned short sT[18 * 18 * 72];  // 46656 B

  float4v acc[16];
#pragma unroll
  for (int pr = 0; pr < 16; ++pr) acc[pr] = (float4v)0.f;

  const float* inB = in + (size_t)b * HW * 64;

  for (int kc = 0; kc < 64; kc += 32) {
    __syncthreads();
    // stage 18x18 x 32ci, split into hi/lo bf16
    for (int j = 0; j < 41; ++j) {
      int s = tid + 256 * j;
      if (s < 10368) {
        int sp = s >> 5, ci = s & 31;
        int lr = sp / 18, lc = sp - lr * 18;
        int gh = th0 + lr - 1, gw = tw0 + lc - 1;
        float v = 0.f;
        if (gh >= 0 && gh < H_ && gw >= 0 && gw < W_)
          v = inB[((size_t)gh * W_ + gw) * 64 + kc + ci];
        unsigned u = __float_as_uint(v);
        unsigned short hi = (unsigned short)(u >> 16);
        float rem = v - __uint_as_float(u & 0xffff0000u);
        unsigned short lo = (unsigned short)(__float_as_uint(rem) >> 16);
        sT[sp * 72 + ci] = hi;
        sT[sp * 72 + 32 + ci] = lo;
      }
    }
    __syncthreads();

    for (int idx = 0; idx < 9; ++idx) {
      const int ky = idx / 3, kx = idx - ky * 3;
      // A fragment: lane holds W[co=16wv+n][ci=kc+8q+j], j=0..7
      const float* wp = wgt + ((size_t)(wv * 16 + n) * 64 + kc + 8 * q) * 9 + idx;
      float wf[8];
#pragma unroll
      for (int j = 0; j < 8; ++j) wf[j] = wp[9 * j];
      short8 ah, al;
#pragma unroll
      for (int j = 0; j < 8; ++j) {
        unsigned u = __float_as_uint(wf[j]);
        ah[j] = (short)(u >> 16);
        float rem = wf[j] - __uint_as_float(u & 0xffff0000u);
        al[j] = (short)(__float_as_uint(rem) >> 16);
      }
      const int cbase = (ky * 18 + n + kx) * 72 + 8 * q;
#pragma unroll
      for (int pr = 0; pr < 16; ++pr) {
        const unsigned short* p = &sT[cbase + pr * (18 * 72)];
        short8 bh = *(const short8*)p;
        short8 bl = *(const short8*)(p + 32);
        acc[pr] = __builtin_amdgcn_mfma_f32_16x16x32_bf16(ah, bh, acc[pr], 0, 0, 0);
        acc[pr] = __builtin_amdgcn_mfma_f32_16x16x32_bf16(al, bh, acc[pr], 0, 0, 0);
        acc[pr] = __builtin_amdgcn_mfma_f32_16x16x32_bf16(ah, bl, acc[pr], 0, 0, 0);
      }
    }
  }

  // epilogue: C/D lane l holds D[row=4q+r][col=n]; co = 16wv+4q+r
  float4v bv = *(const float4v*)&bias[wv * 16 + 4 * q];
#pragma unroll
  for (int pr = 0; pr < 16; ++pr) {
#pragma unroll
    for (int r = 0; r < 4; ++r) {
      int co = wv * 16 + 4 * q + r;
      float v = fmaxf(acc[pr][r] + bv[r], 0.f);
      out[((size_t)b * 64 + co) * HW + (th0 + pr) * W_ + tw0 + n] = v;
    }
  }
}

// ---------------------------------------------------------------------------
// conv3: R3-proven 16x16-tile VALU conv (NCHW in/out), small couts.
// ---------------------------------------------------------------------------
template <int CI, int COG, bool RELU>
__global__ __launch_bounds__(256) void conv16_k(
    const float* __restrict__ in, const float* __restrict__ wgt,
    const float* __restrict__ bias, float* __restrict__ out, int cout) {
  constexpr int CIB = (CI >= 4) ? 4 : CI;
  constexpr int TP = 18;
  constexpr int NST = CIB * TP * TP;
  constexpr int NLD = (NST + 255) / 256;

  const int cog = blockIdx.x;
  const int tile = blockIdx.y;
  const int b = blockIdx.z;
  const int co0 = cog * COG;
  const int th0 = (tile / 14) * 16, tw0 = (tile % 14) * 16;
  const int tid = threadIdx.x;
  const int tx = tid & 15, ty = tid >> 4;

  __shared__ float sW[COG * CI * 12];
  __shared__ float sT[CIB][TP * TP];

  for (int s = tid; s < COG * CI * 12; s += 256) {
    int c = s / (CI * 12);
    int rem = s - c * (CI * 12);
    int ci = rem / 12, r = rem - ci * 12;
    sW[s] = (r < 9) ? wgt[((size_t)(co0 + c) * CI + ci) * 9 + r] : 0.f;
  }

  int po[NLD];
  unsigned okm = 0;
#pragma unroll
  for (int j = 0; j < NLD; ++j) {
    int s = tid + 256 * j;
    int pl = s / (TP * TP), rem = s - pl * (TP * TP);
    int lr = rem / TP, lc = rem - lr * TP;
    int gh = th0 + lr - 1, gw = tw0 + lc - 1;
    bool ok = (s < NST) && gh >= 0 && gh < H_ && gw >= 0 && gw < W_;
    po[j] = ok ? (pl * HW + gh * W_ + gw) : 0;
    if (ok) okm |= (1u << j);
  }

  const float* inB = in + (size_t)b * CI * HW;
  float stg[NLD];
#pragma unroll
  for (int j = 0; j < NLD; ++j) {
    float v = inB[po[j]];
    stg[j] = ((okm >> j) & 1) ? v : 0.f;
  }

  float acc[COG];
#pragma unroll
  for (int c = 0; c < COG; ++c) acc[c] = bias[co0 + c];

  for (int cb = 0; cb < CI; cb += CIB) {
    __syncthreads();
#pragma unroll
    for (int j = 0; j < NLD; ++j) {
      int s = tid + 256 * j;
      if (s < NST) ((float*)sT)[s] = stg[j];
    }
    __syncthreads();
    if (cb + CIB < CI) {
      const float* inN = inB + (size_t)(cb + CIB) * HW;
#pragma unroll
      for (int j = 0; j < NLD; ++j) {
        float v = inN[po[j]];
        stg[j] = ((okm >> j) & 1) ? v : 0.f;
      }
    }
#pragma unroll
    for (int ci = 0; ci < CIB; ++ci) {
      float iv[3][3];
#pragma unroll
      for (int r = 0; r < 3; ++r)
#pragma unroll
        for (int s2 = 0; s2 < 3; ++s2)
          iv[r][s2] = sT[ci][(ty + r) * TP + tx + s2];
#pragma unroll
      for (int c = 0; c < COG; ++c) {
        const float4* wp = (const float4*)&sW[(c * CI + cb + ci) * 12];
        float4 wa = wp[0], wb = wp[1], wc = wp[2];
        acc[c] += iv[0][0] * wa.x + iv[0][1] * wa.y + iv[0][2] * wa.z +
                  iv[1][0] * wa.w + iv[1][1] * wb.x + iv[1][2] * wb.y +
                  iv[2][0] * wb.z + iv[2][1] * wb.w + iv[2][2] * wc.x;
      }
    }
  }

#pragma unroll
  for (int c = 0; c < COG; ++c) {
    int h = th0 + ty, w = tw0 + tx;
    float v = acc[c];
    if (RELU) v = fmaxf(v, 0.f);
    out[((size_t)b * cout + co0 + c) * HW + h * W_ + w] = v;
  }
}

// ---------------------------------------------------------------------------
// Patch extraction: dst[b, n, c*100 + i*10 + j] = src[b, c, 5*q1+i, 5*q2+j]
// ---------------------------------------------------------------------------
__global__ __launch_bounds__(256) void patches_k(const float* __restrict__ src,
                                                 float* __restrict__ dst) {
  int i = blockIdx.x * 256 + threadIdx.x;
  constexpr int TOT = B_ * N_ * D_;
  if (i >= TOT) return;
  int d = i % D_;
  int n = (i / D_) % N_;
  int b = i / (D_ * N_);
  int c = d / 100;
  int rr = (d / 10) % 10;
  int cc = d % 10;
  int q1 = n / N2, q2 = n % N2;
  dst[i] = src[((size_t)(b * 8 + c) * H_ + q1 * 5 + rr) * W_ + q2 * 5 + cc];
}

// ---------------------------------------------------------------------------
// Per-(b,n): sq = ||pe||^2 ; lt = mean of 10x10 log_temp patch. 1 wave each.
// ---------------------------------------------------------------------------
__global__ __launch_bounds__(64) void ltsq_k(const float* __restrict__ pe,
                                             const float* __restrict__ ltmap,
                                             float* __restrict__ lt,
                                             float* __restrict__ sq) {
  int bn = blockIdx.x;
  int b = bn / N_, n = bn % N_;
  int lane = threadIdx.x;
  const float* p = pe + (size_t)bn * D_;
  float s = 0.f;
  for (int i = lane; i < D_; i += 64) {
    float v = p[i];
    s += v * v;
  }
#pragma unroll
  for (int off = 32; off > 0; off >>= 1) s += __shfl_xor(s, off);
  int q1 = n / N2, q2 = n % N2;
  const float* lm = ltmap + (size_t)b * HW;
  float t = 0.f;
  for (int i = lane; i < 100; i += 64)
    t += lm[(q1 * 5 + i / 10) * W_ + q2 * 5 + i % 10];
#pragma unroll
  for (int off = 32; off > 0; off >>= 1) t += __shfl_xor(t, off);
  if (lane == 0) {
    sq[bn] = s;
    lt[bn] = t * 0.01f;
  }
}

// ---------------------------------------------------------------------------
// attn stage 1: one wave per (b,n). Query row in registers, 49 dots,
// K softmax rounds in-wave, write Wk[b,n,m,k].
// ---------------------------------------------------------------------------
__global__ __launch_bounds__(64) void attn_w_k(const float* __restrict__ pe,
                                               const float* __restrict__ lt,
                                               const float* __restrict__ sq,
                                               float* __restrict__ wk) {
  const int n = swiz_n(blockIdx.x);
  if (n >= N_) return;
  const int b = blockIdx.y;
  const int lane = threadIdx.x;
  const int q1 = n / N2, q2 = n % N2;

  const float* peB = pe + (size_t)b * N_ * D_;
  const float* qrow = peB + (size_t)n * D_;
  float q[13];
#pragma unroll
  for (int t = 0; t < 13; ++t) {
    int s = t * 64 + lane;
    q[t] = (s < D_) ? qrow[s] : 0.f;
  }

  __shared__ float sG[M_];

  for (int o1 = 0; o1 < 7; ++o1) {
    int c1 = clampi(q1 + o1 - 3, 0, N1 - 1);
    const float* rowb = peB + (size_t)(c1 * N2) * D_;
#pragma unroll
    for (int o2 = 0; o2 < 7; ++o2) {
      int c2 = clampi(q2 + o2 - 3, 0, N2 - 1);
      const float* crow = rowb + (size_t)c2 * D_;
      float a = 0.f;
#pragma unroll
      for (int t = 0; t < 13; ++t) {
        float v;
        if (t < 12) v = crow[t * 64 + lane];
        else v = (lane < 32) ? crow[768 + lane] : 0.f;
        a += q[t] * v;
      }
#pragma unroll
      for (int off = 32; off > 0; off >>= 1) a += __shfl_xor(a, off);
      if (lane == 0) sG[o1 * 7 + o2] = a;
    }
  }
  __syncthreads();

  const float sqn = sq[b * N_ + n];
  const float itemp = expf(-lt[b * N_ + n]);
  float cur = -INFINITY;
  if (lane < M_) {
    int c1 = clampi(q1 + lane / 7 - 3, 0, N1 - 1);
    int c2 = clampi(q2 + lane % 7 - 3, 0, N2 - 1);
    int cn = c1 * N2 + c2;
    float Dv = -(sqn + sq[b * N_ + cn] - 2.f * sG[lane]);
    cur = (cn == n) ? -1e9f : Dv * itemp;
  }
  float* wrow = wk + (size_t)(b * N_ + n) * (M_ * K_);
#pragma unroll
  for (int k = 0; k < K_; ++k) {
    float mx = cur;
#pragma unroll
    for (int off = 32; off > 0; off >>= 1) mx = fmaxf(mx, __shfl_xor(mx, off));
    float e = (lane < M_) ? expf(cur - mx) : 0.f;
    float ssum = e;
#pragma unroll
    for (int off = 32; off > 0; off >>= 1) ssum += __shfl_xor(ssum, off);
    float w = e / ssum;
    if (lane < M_) wrow[lane * K_ + k] = w;
    cur += log1pf(-fminf(w, 1.f - 1e-6f));
  }
}

// ---------------------------------------------------------------------------
// attn stage 2: one wave per (b, n, d-slice of 64).
// ---------------------------------------------------------------------------
__global__ __launch_bounds__(64) void attn_pv_k(const float* __restrict__ yp,
                                                const float* __restrict__ wk,
                                                float* __restrict__ nb) {
  const int n = swiz_n(blockIdx.x);
  if (n >= N_) return;
  const int b = blockIdx.z;
  const int d = blockIdx.y * 64 + threadIdx.x;
  const bool valid = d < D_;
  const int q1 = n / N2, q2 = n % N2;

  const float* ypB = yp + (size_t)b * N_ * D_;
  const float* wrow = wk + (size_t)(b * N_ + n) * (M_ * K_);

  float acc[K_];
#pragma unroll
  for (int k = 0; k < K_; ++k) acc[k] = 0.f;

#pragma unroll
  for (int o1 = 0; o1 < 7; ++o1) {
    int c1 = clampi(q1 + o1 - 3, 0, N1 - 1);
#pragma unroll
    for (int o2 = 0; o2 < 7; ++o2) {
      int c2 = clampi(q2 + o2 - 3, 0, N2 - 1);
      int cn = c1 * N2 + c2;
      float y = valid ? ypB[(size_t)cn * D_ + d] : 0.f;
      const int m = o1 * 7 + o2;
#pragma unroll
      for (int k = 0; k < K_; ++k) acc[k] += wrow[m * K_ + k] * y;
    }
  }
  if (valid) {
#pragma unroll
    for (int k = 0; k < K_; ++k)
      nb[(((size_t)k * B_ + b) * N_ + n) * D_ + d] = acc[k];
  }
}

// ---------------------------------------------------------------------------
// Fused output: channels 0..7 copy x; channels 8..63 fold-gather from nb.
// ---------------------------------------------------------------------------
__global__ __launch_bounds__(256) void foldcopy_k(const float* __restrict__ x,
                                                  const float* __restrict__ nb,
                                                  float* __restrict__ out) {
  int i = blockIdx.x * 256 + threadIdx.x;
  constexpr int CT = CIN * (K_ + 1);  // 64
  constexpr int TOT = B_ * CT * HW;
  if (i >= TOT) return;
  int w = i % W_;
  int h = (i / W_) % H_;
  int c64 = (i / HW) % CT;
  int b = i / (HW * CT);
  if (c64 < CIN) {
    out[i] = x[((size_t)b * CIN + c64) * HW + h * W_ + w];
    return;
  }
  int k = (c64 - CIN) >> 3, c = (c64 - CIN) & 7;
  int q1lo = max(0, (h - 5) / 5), q1hi = min(N1 - 1, h / 5);
  int q2lo = max(0, (w - 5) / 5), q2hi = min(N2 - 1, w / 5);
  float val = 0.f;
  int cnt = 0;
  for (int q1 = q1lo; q1 <= q1hi; ++q1)
    for (int q2 = q2lo; q2 <= q2hi; ++q2) {
      int i0 = h - 5 * q1, j0 = w - 5 * q2;
      int nn = q1 * N2 + q2;
      val += nb[(((size_t)k * B_ + b) * N_ + nn) * D_ + c * 100 + i0 * 10 + j0];
      ++cnt;
    }
  out[i] = (cnt > 0) ? val / (float)cnt : 0.f;
}

extern "C" void kernel_launch(void* const* d_in, const int* in_sizes, int n_in,
                              void* d_out, int out_size, void* d_ws,
                              size_t ws_size, hipStream_t stream) {
  const float* x   = (const float*)d_in[0];
  const float* w1e = (const float*)d_in[1];
  const float* b1e = (const float*)d_in[2];
  const float* w2e = (const float*)d_in[3];
  const float* b2e = (const float*)d_in[4];
  const float* w3e = (const float*)d_in[5];
  const float* b3e = (const float*)d_in[6];
  const float* w1t = (const float*)d_in[7];
  const float* b1t = (const float*)d_in[8];
  const float* w2t = (const float*)d_in[9];
  const float* b2t = (const float*)d_in[10];
  const float* w3t = (const float*)d_in[11];
  const float* b3t = (const float*)d_in[12];

  float* ws  = (float*)d_ws;
  float* out = (float*)d_out;

  float* h1e = ws + OFF_H1E;   // channels-last
  float* h1t = ws + OFF_H1T;   // channels-last
  float* h2e = ws + OFF_H2E;   // NCHW
  float* h2t = ws + OFF_H2T;   // NCHW
  float* wkb = ws + OFF_WK;
  float* nb  = ws + OFF_NB;
  float* xe  = ws + OFF_XE;
  float* ltm = ws + OFF_LTM;
  float* pe  = ws + OFF_PE;
  float* yp  = ws + OFF_YP;
  float* lt  = ws + OFF_LT;
  float* sqv = ws + OFF_SQ;

  // conv1 (8 -> 64, relu), channels-last output
  conv32_k<CIN, 8, true, true><<<dim3(8, 49, B_), 256, 0, stream>>>(x, w1e, b1e, h1e, F_);
  conv32_k<CIN, 8, true, true><<<dim3(8, 49, B_), 256, 0, stream>>>(x, w1t, b1t, h1t, F_);
  // conv2 (64 -> 64, relu) via MFMA bf16x3, both branches in one dispatch
  conv2_mfma_k<<<dim3(196, 1, 4), 256, 0, stream>>>(h1e, h1t, w2e, w2t, b2e, b2t, h2e, h2t);
  // conv3 (64 -> 8 / 64 -> 1), NCHW
  conv16_k<F_, 8, false><<<dim3(1, 196, B_), 256, 0, stream>>>(h2e, w3e, b3e, xe, E_);
  conv16_k<F_, 1, false><<<dim3(1, 196, B_), 256, 0, stream>>>(h2t, w3t, b3t, ltm, 1);
  // patches
  constexpr int PT = B_ * N_ * D_;
  patches_k<<<(PT + 255) / 256, 256, 0, stream>>>(xe, pe);
  patches_k<<<(PT + 255) / 256, 256, 0, stream>>>(x, yp);
  // per-patch norms + log-temp means
  ltsq_k<<<B_ * N_, 64, 0, stream>>>(pe, ltm, lt, sqv);
  // attention stage 1: weights
  attn_w_k<<<dim3(NSW, B_), 64, 0, stream>>>(pe, lt, sqv, wkb);
  // attention stage 2: weighted neighbor sums (d split into 13 slices)
  attn_pv_k<<<dim3(NSW, 13, B_), 64, 0, stream>>>(yp, wkb, nb);
  // fused fold + x passthrough
  constexpr int FT = B_ * CIN * (K_ + 1) * HW;
  foldcopy_k<<<(FT + 255) / 256, 256, 0, stream>>>(x, nb, out);
}

// Round 7
// 488.604 us; speedup vs baseline: 6.6353x; 1.1982x over previous
//
#include <hip/hip_runtime.h>
#include <math.h>

namespace {
constexpr int B_ = 2, CIN = 8, H_ = 224, W_ = 224;
constexpr int K_ = 7;
constexpr int F_ = 64, E_ = 8;
constexpr int N1 = 43, N2 = 43, N_ = N1 * N2;   // 1849
constexpr int M_ = 49;                           // candidates per query
constexpr int D_ = 800;                          // patch dim (C*P*P)
constexpr int HW = H_ * W_;
constexpr int NSW = 1856;                        // swizzled grid for n (8*232)

// workspace layout (floats).
constexpr size_t FHW = (size_t)B_ * F_ * HW;     // 6,422,528
constexpr size_t OFF_H1E = 0;                    // channels-last [b][h][w][64]
constexpr size_t OFF_H1T = OFF_H1E + FHW;
constexpr size_t OFF_H2E = OFF_H1T + FHW;        // NCHW
constexpr size_t OFF_H2T = OFF_H2E + FHW;
constexpr size_t OFF_WK  = 0;                                  // B*N*343
constexpr size_t OFF_NB  = 1280000;                            // > Wk end
constexpr size_t OFF_XE  = OFF_H2T + FHW;
constexpr size_t OFF_LTM = OFF_XE + (size_t)B_ * E_ * HW;
constexpr size_t OFF_PE  = OFF_LTM + (size_t)B_ * HW;
constexpr size_t OFF_YP  = OFF_PE + (size_t)B_ * N_ * D_;
constexpr size_t OFF_LT  = OFF_YP + (size_t)B_ * N_ * D_;
constexpr size_t OFF_SQ  = OFF_LT + (size_t)B_ * N_;
// conv2 prepped weights overlap the xe region (consumed by conv2 before
// conv16 writes xe): 2 buffers x 294912 ushorts = 294,912 floats < 802,816.
constexpr int WPREP_N = 294912;  // 2br * 2kcb * 9idx * 4wv * 64lane * 8j

__device__ __forceinline__ int clampi(int v, int lo, int hi) {
  return min(max(v, lo), hi);
}
__device__ __forceinline__ int swiz_n(int xr) { return (xr & 7) * 232 + (xr >> 3); }

typedef __attribute__((ext_vector_type(8))) short short8;
typedef __attribute__((ext_vector_type(4))) float float4v;
} // namespace

// ---------------------------------------------------------------------------
// conv1: R3-proven VALU conv (weights in LDS, stride-1 tx -> 0 conflicts),
// 32x32 tile, 8 couts/block, 4 rows/thread. CL=true stores channels-last.
// ---------------------------------------------------------------------------
template <int CI, int COG, bool RELU, bool CL>
__global__ __launch_bounds__(256) void conv32_k(
    const float* __restrict__ in, const float* __restrict__ wgt,
    const float* __restrict__ bias, float* __restrict__ out, int cout) {
  constexpr int CIB = (CI >= 4) ? 4 : CI;
  constexpr int TP = 34;
  constexpr int NST = CIB * TP * TP;
  constexpr int NLD = (NST + 255) / 256;

  const int cog = blockIdx.x;
  const int tile = blockIdx.y;
  const int b = blockIdx.z;
  const int co0 = cog * COG;
  const int th0 = (tile / 7) * 32, tw0 = (tile % 7) * 32;
  const int tid = threadIdx.x;
  const int tx = tid & 31, ty = tid >> 5;

  __shared__ float sW[COG * CI * 12];
  __shared__ float sT[CIB][TP * TP];

  for (int s = tid; s < COG * CI * 12; s += 256) {
    int c = s / (CI * 12);
    int rem = s - c * (CI * 12);
    int ci = rem / 12, r = rem - ci * 12;
    sW[s] = (r < 9) ? wgt[((size_t)(co0 + c) * CI + ci) * 9 + r] : 0.f;
  }

  int po[NLD];
  unsigned okm = 0;
#pragma unroll
  for (int j = 0; j < NLD; ++j) {
    int s = tid + 256 * j;
    int pl = s / (TP * TP), rem = s - pl * (TP * TP);
    int lr = rem / TP, lc = rem - lr * TP;
    int gh = th0 + lr - 1, gw = tw0 + lc - 1;
    bool ok = (s < NST) && gh >= 0 && gh < H_ && gw >= 0 && gw < W_;
    po[j] = ok ? (pl * HW + gh * W_ + gw) : 0;
    if (ok) okm |= (1u << j);
  }

  const float* inB = in + (size_t)b * CI * HW;
  float stg[NLD];
#pragma unroll
  for (int j = 0; j < NLD; ++j) {
    float v = inB[po[j]];
    stg[j] = ((okm >> j) & 1) ? v : 0.f;
  }

  float acc[COG][4];
#pragma unroll
  for (int c = 0; c < COG; ++c) {
    float bv = bias[co0 + c];
#pragma unroll
    for (int r = 0; r < 4; ++r) acc[c][r] = bv;
  }

  for (int cb = 0; cb < CI; cb += CIB) {
    __syncthreads();
#pragma unroll
    for (int j = 0; j < NLD; ++j) {
      int s = tid + 256 * j;
      if (s < NST) ((float*)sT)[s] = stg[j];
    }
    __syncthreads();
    if (cb + CIB < CI) {
      const float* inN = inB + (size_t)(cb + CIB) * HW;
#pragma unroll
      for (int j = 0; j < NLD; ++j) {
        float v = inN[po[j]];
        stg[j] = ((okm >> j) & 1) ? v : 0.f;
      }
    }
#pragma unroll
    for (int ci = 0; ci < CIB; ++ci) {
      float iv[6][3];
#pragma unroll
      for (int r = 0; r < 6; ++r)
#pragma unroll
        for (int s2 = 0; s2 < 3; ++s2)
          iv[r][s2] = sT[ci][(4 * ty + r) * 34 + tx + s2];
#pragma unroll
      for (int c = 0; c < COG; ++c) {
        const float4* wp = (const float4*)&sW[(c * CI + cb + ci) * 12];
        float4 wa = wp[0], wb = wp[1], wc = wp[2];
#pragma unroll
        for (int dy = 0; dy < 4; ++dy) {
          acc[c][dy] += iv[dy + 0][0] * wa.x + iv[dy + 0][1] * wa.y +
                        iv[dy + 0][2] * wa.z + iv[dy + 1][0] * wa.w +
                        iv[dy + 1][1] * wb.x + iv[dy + 1][2] * wb.y +
                        iv[dy + 2][0] * wb.z + iv[dy + 2][1] * wb.w +
                        iv[dy + 2][2] * wc.x;
        }
      }
    }
  }

#pragma unroll
  for (int c = 0; c < COG; ++c)
#pragma unroll
    for (int dy = 0; dy < 4; ++dy) {
      int h = th0 + 4 * ty + dy, w = tw0 + tx;
      float v = acc[c][dy];
      if (RELU) v = fmaxf(v, 0.f);
      if (CL)
        out[(((size_t)b * H_ + h) * W_ + w) * 64 + co0 + c] = v;
      else
        out[((size_t)b * cout + co0 + c) * HW + h * W_ + w] = v;
    }
}

// ---------------------------------------------------------------------------
// Weight prep for MFMA conv2: split fp32 -> bf16 hi/lo, laid out in exact
// A-fragment order: flat = ((((br*2+kcb)*9+idx)*4+wv)*64+lane)*8+j with
// co = wv*16 + (lane&15), ci = kcb*32 + 8*(lane>>4) + j.
// ---------------------------------------------------------------------------
__global__ __launch_bounds__(256) void wprep_k(const float* __restrict__ w_e,
                                               const float* __restrict__ w_t,
                                               unsigned short* __restrict__ whi,
                                               unsigned short* __restrict__ wlo) {
  int t = blockIdx.x * 256 + threadIdx.x;
  if (t >= WPREP_N) return;
  int j = t & 7;
  int lane = (t >> 3) & 63;
  int wv = (t >> 9) & 3;
  int t2 = t >> 11;          // (br*2+kcb)*9+idx
  int idx = t2 % 9;
  int t3 = t2 / 9;
  int kcb = t3 & 1;
  int br = t3 >> 1;
  const float* wgt = br ? w_t : w_e;
  int co = wv * 16 + (lane & 15);
  int ci = kcb * 32 + 8 * (lane >> 4) + j;
  float v = wgt[((size_t)co * 64 + ci) * 9 + idx];
  unsigned u = __float_as_uint(v);
  unsigned short hi = (unsigned short)(u >> 16);
  float rem = v - __uint_as_float(u & 0xffff0000u);
  unsigned short lo = (unsigned short)(__float_as_uint(rem) >> 16);
  whi[t] = hi;
  wlo[t] = lo;
}

// ---------------------------------------------------------------------------
// conv2 (64->64, relu) via MFMA bf16 3-term hi/lo split. Row-loop structure:
// stage 18x18x32ci (hi|lo) in LDS; A-fragments preloaded from the prepped
// weight buffers (18 coalesced 16B loads per wave per kc, no VALU); then for
// each staged row r, read 6 B-fragments and fire all valid (ky,kx) MFMAs
// into acc[r-ky]. LDS reads: 108/wave/kc (was 288).
// ---------------------------------------------------------------------------
__global__ __launch_bounds__(256) void conv2_mfma_k(
    const float* __restrict__ in_e, const float* __restrict__ in_t,
    const unsigned short* __restrict__ whi, const unsigned short* __restrict__ wlo,
    const float* __restrict__ b_e, const float* __restrict__ b_t,
    float* __restrict__ out_e, float* __restrict__ out_t) {
  const int tile = blockIdx.x;
  const int b = blockIdx.z & 1;
  const int br = blockIdx.z >> 1;
  const float* in = br ? in_t : in_e;
  const float* bias = br ? b_t : b_e;
  float* out = br ? out_t : out_e;

  const int th0 = (tile / 14) * 16, tw0 = (tile % 14) * 16;
  const int tid = threadIdx.x;
  const int wv = tid >> 6, lane = tid & 63;
  const int q = lane >> 4, n = lane & 15;

  __shared__ unsigned short sT[18 * 18 * 72];  // 46656 B
  unsigned* sT32 = (unsigned*)sT;

  float4v acc[16];
#pragma unroll
  for (int pr = 0; pr < 16; ++pr) acc[pr] = (float4v)0.f;

  const float* inB = in + (size_t)b * HW * 64;
  const short8* whi8 = (const short8*)whi;
  const short8* wlo8 = (const short8*)wlo;

  for (int kcb = 0; kcb < 2; ++kcb) {
    __syncthreads();
    // stage: 324 spatial x 32 ci as float2 per thread -> packed dword writes
    for (int jj = 0; jj < 21; ++jj) {
      int s = tid + 256 * jj;
      if (s < 5184) {
        int sp = s >> 4, cp = s & 15;
        int lr = sp / 18, lc = sp - lr * 18;
        int gh = th0 + lr - 1, gw = tw0 + lc - 1;
        float vx = 0.f, vy = 0.f;
        if (gh >= 0 && gh < H_ && gw >= 0 && gw < W_) {
          const float2 vv =
              *(const float2*)&inB[((size_t)gh * W_ + gw) * 64 + kcb * 32 + 2 * cp];
          vx = vv.x; vy = vv.y;
        }
        unsigned u0 = __float_as_uint(vx), u1 = __float_as_uint(vy);
        float r0 = vx - __uint_as_float(u0 & 0xffff0000u);
        float r1 = vy - __uint_as_float(u1 & 0xffff0000u);
        unsigned l0 = __float_as_uint(r0) >> 16, l1 = __float_as_uint(r1) >> 16;
        sT32[sp * 36 + cp] = (u0 >> 16) | ((u1 >> 16) << 16);
        sT32[sp * 36 + 16 + cp] = l0 | (l1 << 16);
      }
    }
    __syncthreads();

    // A fragments: 9 idx x (hi, lo), coalesced 16B loads
    short8 Ah[9], Al[9];
    const int abase = (((br * 2 + kcb) * 9) * 4 + wv) * 64 + lane;  // +256/idx
#pragma unroll
    for (int idx = 0; idx < 9; ++idx) {
      Ah[idx] = whi8[abase + idx * 256];
      Al[idx] = wlo8[abase + idx * 256];
    }

#pragma unroll
    for (int r = 0; r < 18; ++r) {
      short8 Bh[3], Bl[3];
#pragma unroll
      for (int kx = 0; kx < 3; ++kx) {
        const unsigned short* p = &sT[(r * 18 + n + kx) * 72 + 8 * q];
        Bh[kx] = *(const short8*)p;
        Bl[kx] = *(const short8*)(p + 32);
      }
#pragma unroll
      for (int ky = 0; ky < 3; ++ky) {
        const int pr = r - ky;
        if (pr >= 0 && pr < 16) {
#pragma unroll
          for (int kx = 0; kx < 3; ++kx) {
            const int idx = ky * 3 + kx;
            acc[pr] = __builtin_amdgcn_mfma_f32_16x16x32_bf16(Ah[idx], Bh[kx], acc[pr], 0, 0, 0);
            acc[pr] = __builtin_amdgcn_mfma_f32_16x16x32_bf16(Al[idx], Bh[kx], acc[pr], 0, 0, 0);
            acc[pr] = __builtin_amdgcn_mfma_f32_16x16x32_bf16(Ah[idx], Bl[kx], acc[pr], 0, 0, 0);
          }
        }
      }
    }
  }

  // epilogue: lane holds D[row=4q+r][col=n]; co = 16wv+4q+r
  float4v bv = *(const float4v*)&bias[wv * 16 + 4 * q];
#pragma unroll
  for (int pr = 0; pr < 16; ++pr) {
#pragma unroll
    for (int r = 0; r < 4; ++r) {
      int co = wv * 16 + 4 * q + r;
      float v = fmaxf(acc[pr][r] + bv[r], 0.f);
      out[((size_t)b * 64 + co) * HW + (th0 + pr) * W_ + tw0 + n] = v;
    }
  }
}

// ---------------------------------------------------------------------------
// conv3: R3-proven 16x16-tile VALU conv (NCHW in/out), small couts.
// ---------------------------------------------------------------------------
template <int CI, int COG, bool RELU>
__global__ __launch_bounds__(256) void conv16_k(
    const float* __restrict__ in, const float* __restrict__ wgt,
    const float* __restrict__ bias, float* __restrict__ out, int cout) {
  constexpr int CIB = (CI >= 4) ? 4 : CI;
  constexpr int TP = 18;
  constexpr int NST = CIB * TP * TP;
  constexpr int NLD = (NST + 255) / 256;

  const int cog = blockIdx.x;
  const int tile = blockIdx.y;
  const int b = blockIdx.z;
  const int co0 = cog * COG;
  const int th0 = (tile / 14) * 16, tw0 = (tile % 14) * 16;
  const int tid = threadIdx.x;
  const int tx = tid & 15, ty = tid >> 4;

  __shared__ float sW[COG * CI * 12];
  __shared__ float sT[CIB][TP * TP];

  for (int s = tid; s < COG * CI * 12; s += 256) {
    int c = s / (CI * 12);
    int rem = s - c * (CI * 12);
    int ci = rem / 12, r = rem - ci * 12;
    sW[s] = (r < 9) ? wgt[((size_t)(co0 + c) * CI + ci) * 9 + r] : 0.f;
  }

  int po[NLD];
  unsigned okm = 0;
#pragma unroll
  for (int j = 0; j < NLD; ++j) {
    int s = tid + 256 * j;
    int pl = s / (TP * TP), rem = s - pl * (TP * TP);
    int lr = rem / TP, lc = rem - lr * TP;
    int gh = th0 + lr - 1, gw = tw0 + lc - 1;
    bool ok = (s < NST) && gh >= 0 && gh < H_ && gw >= 0 && gw < W_;
    po[j] = ok ? (pl * HW + gh * W_ + gw) : 0;
    if (ok) okm |= (1u << j);
  }

  const float* inB = in + (size_t)b * CI * HW;
  float stg[NLD];
#pragma unroll
  for (int j = 0; j < NLD; ++j) {
    float v = inB[po[j]];
    stg[j] = ((okm >> j) & 1) ? v : 0.f;
  }

  float acc[COG];
#pragma unroll
  for (int c = 0; c < COG; ++c) acc[c] = bias[co0 + c];

  for (int cb = 0; cb < CI; cb += CIB) {
    __syncthreads();
#pragma unroll
    for (int j = 0; j < NLD; ++j) {
      int s = tid + 256 * j;
      if (s < NST) ((float*)sT)[s] = stg[j];
    }
    __syncthreads();
    if (cb + CIB < CI) {
      const float* inN = inB + (size_t)(cb + CIB) * HW;
#pragma unroll
      for (int j = 0; j < NLD; ++j) {
        float v = inN[po[j]];
        stg[j] = ((okm >> j) & 1) ? v : 0.f;
      }
    }
#pragma unroll
    for (int ci = 0; ci < CIB; ++ci) {
      float iv[3][3];
#pragma unroll
      for (int r = 0; r < 3; ++r)
#pragma unroll
        for (int s2 = 0; s2 < 3; ++s2)
          iv[r][s2] = sT[ci][(ty + r) * TP + tx + s2];
#pragma unroll
      for (int c = 0; c < COG; ++c) {
        const float4* wp = (const float4*)&sW[(c * CI + cb + ci) * 12];
        float4 wa = wp[0], wb = wp[1], wc = wp[2];
        acc[c] += iv[0][0] * wa.x + iv[0][1] * wa.y + iv[0][2] * wa.z +
                  iv[1][0] * wa.w + iv[1][1] * wb.x + iv[1][2] * wb.y +
                  iv[2][0] * wb.z + iv[2][1] * wb.w + iv[2][2] * wc.x;
      }
    }
  }

#pragma unroll
  for (int c = 0; c < COG; ++c) {
    int h = th0 + ty, w = tw0 + tx;
    float v = acc[c];
    if (RELU) v = fmaxf(v, 0.f);
    out[((size_t)b * cout + co0 + c) * HW + h * W_ + w] = v;
  }
}

// ---------------------------------------------------------------------------
// Patch extraction: dst[b, n, c*100 + i*10 + j] = src[b, c, 5*q1+i, 5*q2+j]
// ---------------------------------------------------------------------------
__global__ __launch_bounds__(256) void patches_k(const float* __restrict__ src,
                                                 float* __restrict__ dst) {
  int i = blockIdx.x * 256 + threadIdx.x;
  constexpr int TOT = B_ * N_ * D_;
  if (i >= TOT) return;
  int d = i % D_;
  int n = (i / D_) % N_;
  int b = i / (D_ * N_);
  int c = d / 100;
  int rr = (d / 10) % 10;
  int cc = d % 10;
  int q1 = n / N2, q2 = n % N2;
  dst[i] = src[((size_t)(b * 8 + c) * H_ + q1 * 5 + rr) * W_ + q2 * 5 + cc];
}

// ---------------------------------------------------------------------------
// Per-(b,n): sq = ||pe||^2 ; lt = mean of 10x10 log_temp patch. 1 wave each.
// ---------------------------------------------------------------------------
__global__ __launch_bounds__(64) void ltsq_k(const float* __restrict__ pe,
                                             const float* __restrict__ ltmap,
                                             float* __restrict__ lt,
                                             float* __restrict__ sq) {
  int bn = blockIdx.x;
  int b = bn / N_, n = bn % N_;
  int lane = threadIdx.x;
  const float* p = pe + (size_t)bn * D_;
  float s = 0.f;
  for (int i = lane; i < D_; i += 64) {
    float v = p[i];
    s += v * v;
  }
#pragma unroll
  for (int off = 32; off > 0; off >>= 1) s += __shfl_xor(s, off);
  int q1 = n / N2, q2 = n % N2;
  const float* lm = ltmap + (size_t)b * HW;
  float t = 0.f;
  for (int i = lane; i < 100; i += 64)
    t += lm[(q1 * 5 + i / 10) * W_ + q2 * 5 + i % 10];
#pragma unroll
  for (int off = 32; off > 0; off >>= 1) t += __shfl_xor(t, off);
  if (lane == 0) {
    sq[bn] = s;
    lt[bn] = t * 0.01f;
  }
}

// ---------------------------------------------------------------------------
// attn stage 1: one wave per (b,n). Query row in registers, 49 dots,
// K softmax rounds in-wave, write Wk[b,n,m,k].
// ---------------------------------------------------------------------------
__global__ __launch_bounds__(64) void attn_w_k(const float* __restrict__ pe,
                                               const float* __restrict__ lt,
                                               const float* __restrict__ sq,
                                               float* __restrict__ wk) {
  const int n = swiz_n(blockIdx.x);
  if (n >= N_) return;
  const int b = blockIdx.y;
  const int lane = threadIdx.x;
  const int q1 = n / N2, q2 = n % N2;

  const float* peB = pe + (size_t)b * N_ * D_;
  const float* qrow = peB + (size_t)n * D_;
  float q[13];
#pragma unroll
  for (int t = 0; t < 13; ++t) {
    int s = t * 64 + lane;
    q[t] = (s < D_) ? qrow[s] : 0.f;
  }

  __shared__ float sG[M_];

  for (int o1 = 0; o1 < 7; ++o1) {
    int c1 = clampi(q1 + o1 - 3, 0, N1 - 1);
    const float* rowb = peB + (size_t)(c1 * N2) * D_;
#pragma unroll
    for (int o2 = 0; o2 < 7; ++o2) {
      int c2 = clampi(q2 + o2 - 3, 0, N2 - 1);
      const float* crow = rowb + (size_t)c2 * D_;
      float a = 0.f;
#pragma unroll
      for (int t = 0; t < 13; ++t) {
        float v;
        if (t < 12) v = crow[t * 64 + lane];
        else v = (lane < 32) ? crow[768 + lane] : 0.f;
        a += q[t] * v;
      }
#pragma unroll
      for (int off = 32; off > 0; off >>= 1) a += __shfl_xor(a, off);
      if (lane == 0) sG[o1 * 7 + o2] = a;
    }
  }
  __syncthreads();

  const float sqn = sq[b * N_ + n];
  const float itemp = expf(-lt[b * N_ + n]);
  float cur = -INFINITY;
  if (lane < M_) {
    int c1 = clampi(q1 + lane / 7 - 3, 0, N1 - 1);
    int c2 = clampi(q2 + lane % 7 - 3, 0, N2 - 1);
    int cn = c1 * N2 + c2;
    float Dv = -(sqn + sq[b * N_ + cn] - 2.f * sG[lane]);
    cur = (cn == n) ? -1e9f : Dv * itemp;
  }
  float* wrow = wk + (size_t)(b * N_ + n) * (M_ * K_);
#pragma unroll
  for (int k = 0; k < K_; ++k) {
    float mx = cur;
#pragma unroll
    for (int off = 32; off > 0; off >>= 1) mx = fmaxf(mx, __shfl_xor(mx, off));
    float e = (lane < M_) ? expf(cur - mx) : 0.f;
    float ssum = e;
#pragma unroll
    for (int off = 32; off > 0; off >>= 1) ssum += __shfl_xor(ssum, off);
    float w = e / ssum;
    if (lane < M_) wrow[lane * K_ + k] = w;
    cur += log1pf(-fminf(w, 1.f - 1e-6f));
  }
}

// ---------------------------------------------------------------------------
// attn stage 2: one wave per (b, n, d-slice of 64).
// ---------------------------------------------------------------------------
__global__ __launch_bounds__(64) void attn_pv_k(const float* __restrict__ yp,
                                                const float* __restrict__ wk,
                                                float* __restrict__ nb) {
  const int n = swiz_n(blockIdx.x);
  if (n >= N_) return;
  const int b = blockIdx.z;
  const int d = blockIdx.y * 64 + threadIdx.x;
  const bool valid = d < D_;
  const int q1 = n / N2, q2 = n % N2;

  const float* ypB = yp + (size_t)b * N_ * D_;
  const float* wrow = wk + (size_t)(b * N_ + n) * (M_ * K_);

  float acc[K_];
#pragma unroll
  for (int k = 0; k < K_; ++k) acc[k] = 0.f;

#pragma unroll
  for (int o1 = 0; o1 < 7; ++o1) {
    int c1 = clampi(q1 + o1 - 3, 0, N1 - 1);
#pragma unroll
    for (int o2 = 0; o2 < 7; ++o2) {
      int c2 = clampi(q2 + o2 - 3, 0, N2 - 1);
      int cn = c1 * N2 + c2;
      float y = valid ? ypB[(size_t)cn * D_ + d] : 0.f;
      const int m = o1 * 7 + o2;
#pragma unroll
      for (int k = 0; k < K_; ++k) acc[k] += wrow[m * K_ + k] * y;
    }
  }
  if (valid) {
#pragma unroll
    for (int k = 0; k < K_; ++k)
      nb[(((size_t)k * B_ + b) * N_ + n) * D_ + d] = acc[k];
  }
}

// ---------------------------------------------------------------------------
// Fused output: channels 0..7 copy x; channels 8..63 fold-gather from nb.
// ---------------------------------------------------------------------------
__global__ __launch_bounds__(256) void foldcopy_k(const float* __restrict__ x,
                                                  const float* __restrict__ nb,
                                                  float* __restrict__ out) {
  int i = blockIdx.x * 256 + threadIdx.x;
  constexpr int CT = CIN * (K_ + 1);  // 64
  constexpr int TOT = B_ * CT * HW;
  if (i >= TOT) return;
  int w = i % W_;
  int h = (i / W_) % H_;
  int c64 = (i / HW) % CT;
  int b = i / (HW * CT);
  if (c64 < CIN) {
    out[i] = x[((size_t)b * CIN + c64) * HW + h * W_ + w];
    return;
  }
  int k = (c64 - CIN) >> 3, c = (c64 - CIN) & 7;
  int q1lo = max(0, (h - 5) / 5), q1hi = min(N1 - 1, h / 5);
  int q2lo = max(0, (w - 5) / 5), q2hi = min(N2 - 1, w / 5);
  float val = 0.f;
  int cnt = 0;
  for (int q1 = q1lo; q1 <= q1hi; ++q1)
    for (int q2 = q2lo; q2 <= q2hi; ++q2) {
      int i0 = h - 5 * q1, j0 = w - 5 * q2;
      int nn = q1 * N2 + q2;
      val += nb[(((size_t)k * B_ + b) * N_ + nn) * D_ + c * 100 + i0 * 10 + j0];
      ++cnt;
    }
  out[i] = (cnt > 0) ? val / (float)cnt : 0.f;
}

extern "C" void kernel_launch(void* const* d_in, const int* in_sizes, int n_in,
                              void* d_out, int out_size, void* d_ws,
                              size_t ws_size, hipStream_t stream) {
  const float* x   = (const float*)d_in[0];
  const float* w1e = (const float*)d_in[1];
  const float* b1e = (const float*)d_in[2];
  const float* w2e = (const float*)d_in[3];
  const float* b2e = (const float*)d_in[4];
  const float* w3e = (const float*)d_in[5];
  const float* b3e = (const float*)d_in[6];
  const float* w1t = (const float*)d_in[7];
  const float* b1t = (const float*)d_in[8];
  const float* w2t = (const float*)d_in[9];
  const float* b2t = (const float*)d_in[10];
  const float* w3t = (const float*)d_in[11];
  const float* b3t = (const float*)d_in[12];

  float* ws  = (float*)d_ws;
  float* out = (float*)d_out;

  float* h1e = ws + OFF_H1E;   // channels-last
  float* h1t = ws + OFF_H1T;   // channels-last
  float* h2e = ws + OFF_H2E;   // NCHW
  float* h2t = ws + OFF_H2T;   // NCHW
  float* wkb = ws + OFF_WK;
  float* nb  = ws + OFF_NB;
  float* xe  = ws + OFF_XE;
  float* ltm = ws + OFF_LTM;
  float* pe  = ws + OFF_PE;
  float* yp  = ws + OFF_YP;
  float* lt  = ws + OFF_LT;
  float* sqv = ws + OFF_SQ;
  // prepped conv2 weights overlap xe (consumed before conv16 writes xe)
  unsigned short* whi = (unsigned short*)(ws + OFF_XE);
  unsigned short* wlo = whi + WPREP_N;

  // weight prep (independent of conv1)
  wprep_k<<<(WPREP_N + 255) / 256, 256, 0, stream>>>(w2e, w2t, whi, wlo);
  // conv1 (8 -> 64, relu), channels-last output
  conv32_k<CIN, 8, true, true><<<dim3(8, 49, B_), 256, 0, stream>>>(x, w1e, b1e, h1e, F_);
  conv32_k<CIN, 8, true, true><<<dim3(8, 49, B_), 256, 0, stream>>>(x, w1t, b1t, h1t, F_);
  // conv2 (64 -> 64, relu) via MFMA, both branches + batches in one dispatch
  conv2_mfma_k<<<dim3(196, 1, 4), 256, 0, stream>>>(h1e, h1t, whi, wlo, b2e, b2t, h2e, h2t);
  // conv3 (64 -> 8 / 64 -> 1), NCHW
  conv16_k<F_, 8, false><<<dim3(1, 196, B_), 256, 0, stream>>>(h2e, w3e, b3e, xe, E_);
  conv16_k<F_, 1, false><<<dim3(1, 196, B_), 256, 0, stream>>>(h2t, w3t, b3t, ltm, 1);
  // patches
  constexpr int PT = B_ * N_ * D_;
  patches_k<<<(PT + 255) / 256, 256, 0, stream>>>(xe, pe);
  patches_k<<<(PT + 255) / 256, 256, 0, stream>>>(x, yp);
  // per-patch norms + log-temp means
  ltsq_k<<<B_ * N_, 64, 0, stream>>>(pe, ltm, lt, sqv);
  // attention stage 1: weights
  attn_w_k<<<dim3(NSW, B_), 64, 0, stream>>>(pe, lt, sqv, wkb);
  // attention stage 2: weighted neighbor sums (d split into 13 slices)
  attn_pv_k<<<dim3(NSW, 13, B_), 64, 0, stream>>>(yp, wkb, nb);
  // fused fold + x passthrough
  constexpr int FT = B_ * CIN * (K_ + 1) * HW;
  foldcopy_k<<<(FT + 255) / 256, 256, 0, stream>>>(x, nb, out);
}

// Round 8
// 483.687 us; speedup vs baseline: 6.7028x; 1.0102x over previous
//
#include <hip/hip_runtime.h>
#include <math.h>

namespace {
constexpr int B_ = 2, CIN = 8, H_ = 224, W_ = 224;
constexpr int K_ = 7;
constexpr int F_ = 64, E_ = 8;
constexpr int N1 = 43, N2 = 43, N_ = N1 * N2;   // 1849
constexpr int M_ = 49;                           // candidates per query
constexpr int D_ = 800;                          // patch dim (C*P*P)
constexpr int HW = H_ * W_;

// workspace layout (floats).
constexpr size_t FHW = (size_t)B_ * F_ * HW;     // 6,422,528
constexpr size_t OFF_H1E = 0;                    // channels-last [b][h][w][64]
constexpr size_t OFF_H1T = OFF_H1E + FHW;
constexpr size_t OFF_H2E = OFF_H1T + FHW;        // NCHW
constexpr size_t OFF_H2T = OFF_H2E + FHW;
constexpr size_t OFF_WK  = 0;                                  // B*N*343
constexpr size_t OFF_NB  = 1280000;                            // > Wk end
constexpr size_t OFF_XE  = OFF_H2T + FHW;
constexpr size_t OFF_LTM = OFF_XE + (size_t)B_ * E_ * HW;
constexpr size_t OFF_PE  = OFF_LTM + (size_t)B_ * HW;
constexpr size_t OFF_YP  = OFF_PE + (size_t)B_ * N_ * D_;
constexpr size_t OFF_LT  = OFF_YP + (size_t)B_ * N_ * D_;
constexpr size_t OFF_SQ  = OFF_LT + (size_t)B_ * N_;
// conv2 prepped weights overlap the xe region (consumed by conv2 before
// conv3 writes xe): 2 buffers x 294912 ushorts = 294,912 floats < 802,816.
constexpr int WPREP_N = 294912;  // 2br * 2kcb * 9idx * 4wv * 64lane * 8j

__device__ __forceinline__ int clampi(int v, int lo, int hi) {
  return min(max(v, lo), hi);
}

typedef __attribute__((ext_vector_type(8))) short short8;
typedef __attribute__((ext_vector_type(4))) float float4v;
} // namespace

// ---------------------------------------------------------------------------
// conv1 (8->64, relu), e+t merged in one dispatch (z: bit0=batch, bit1=branch)
// R3-proven structure: weights in LDS, 32x32 tile, stride-1 tx (0 conflicts),
// 4 rows/thread, channels-last output for the MFMA conv2.
// ---------------------------------------------------------------------------
__global__ __launch_bounds__(256) void conv1m_k(
    const float* __restrict__ x,
    const float* __restrict__ w_e, const float* __restrict__ b_e, float* __restrict__ o_e,
    const float* __restrict__ w_t, const float* __restrict__ b_t, float* __restrict__ o_t) {
  constexpr int CI = 8, COG = 8, CIB = 4, TP = 34;
  constexpr int NST = CIB * TP * TP;
  constexpr int NLD = (NST + 255) / 256;

  const int cog = blockIdx.x;
  const int tile = blockIdx.y;
  const int b = blockIdx.z & 1, br = blockIdx.z >> 1;
  const float* wgt = br ? w_t : w_e;
  const float* bias = br ? b_t : b_e;
  float* out = br ? o_t : o_e;
  const int co0 = cog * COG;
  const int th0 = (tile / 7) * 32, tw0 = (tile % 7) * 32;
  const int tid = threadIdx.x;
  const int tx = tid & 31, ty = tid >> 5;

  __shared__ float sW[COG * CI * 12];
  __shared__ float sT[CIB][TP * TP];

  for (int s = tid; s < COG * CI * 12; s += 256) {
    int c = s / (CI * 12);
    int rem = s - c * (CI * 12);
    int ci = rem / 12, r = rem - ci * 12;
    sW[s] = (r < 9) ? wgt[((size_t)(co0 + c) * CI + ci) * 9 + r] : 0.f;
  }

  int po[NLD];
  unsigned okm = 0;
#pragma unroll
  for (int j = 0; j < NLD; ++j) {
    int s = tid + 256 * j;
    int pl = s / (TP * TP), rem = s - pl * (TP * TP);
    int lr = rem / TP, lc = rem - lr * TP;
    int gh = th0 + lr - 1, gw = tw0 + lc - 1;
    bool ok = (s < NST) && gh >= 0 && gh < H_ && gw >= 0 && gw < W_;
    po[j] = ok ? (pl * HW + gh * W_ + gw) : 0;
    if (ok) okm |= (1u << j);
  }

  const float* inB = x + (size_t)b * CI * HW;
  float stg[NLD];
#pragma unroll
  for (int j = 0; j < NLD; ++j) {
    float v = inB[po[j]];
    stg[j] = ((okm >> j) & 1) ? v : 0.f;
  }

  float acc[COG][4];
#pragma unroll
  for (int c = 0; c < COG; ++c) {
    float bv = bias[co0 + c];
#pragma unroll
    for (int r = 0; r < 4; ++r) acc[c][r] = bv;
  }

  for (int cb = 0; cb < CI; cb += CIB) {
    __syncthreads();
#pragma unroll
    for (int j = 0; j < NLD; ++j) {
      int s = tid + 256 * j;
      if (s < NST) ((float*)sT)[s] = stg[j];
    }
    __syncthreads();
    if (cb + CIB < CI) {
      const float* inN = inB + (size_t)(cb + CIB) * HW;
#pragma unroll
      for (int j = 0; j < NLD; ++j) {
        float v = inN[po[j]];
        stg[j] = ((okm >> j) & 1) ? v : 0.f;
      }
    }
#pragma unroll
    for (int ci = 0; ci < CIB; ++ci) {
      float iv[6][3];
#pragma unroll
      for (int r = 0; r < 6; ++r)
#pragma unroll
        for (int s2 = 0; s2 < 3; ++s2)
          iv[r][s2] = sT[ci][(4 * ty + r) * 34 + tx + s2];
#pragma unroll
      for (int c = 0; c < COG; ++c) {
        const float4* wp = (const float4*)&sW[(c * CI + cb + ci) * 12];
        float4 wa = wp[0], wb = wp[1], wc = wp[2];
#pragma unroll
        for (int dy = 0; dy < 4; ++dy) {
          acc[c][dy] += iv[dy + 0][0] * wa.x + iv[dy + 0][1] * wa.y +
                        iv[dy + 0][2] * wa.z + iv[dy + 1][0] * wa.w +
                        iv[dy + 1][1] * wb.x + iv[dy + 1][2] * wb.y +
                        iv[dy + 2][0] * wb.z + iv[dy + 2][1] * wb.w +
                        iv[dy + 2][2] * wc.x;
        }
      }
    }
  }

#pragma unroll
  for (int c = 0; c < COG; ++c)
#pragma unroll
    for (int dy = 0; dy < 4; ++dy) {
      int h = th0 + 4 * ty + dy, w = tw0 + tx;
      out[(((size_t)b * H_ + h) * W_ + w) * 64 + co0 + c] = fmaxf(acc[c][dy], 0.f);
    }
}

// ---------------------------------------------------------------------------
// Weight prep for MFMA conv2 (unchanged from R7).
// ---------------------------------------------------------------------------
__global__ __launch_bounds__(256) void wprep_k(const float* __restrict__ w_e,
                                               const float* __restrict__ w_t,
                                               unsigned short* __restrict__ whi,
                                               unsigned short* __restrict__ wlo) {
  int t = blockIdx.x * 256 + threadIdx.x;
  if (t >= WPREP_N) return;
  int j = t & 7;
  int lane = (t >> 3) & 63;
  int wv = (t >> 9) & 3;
  int t2 = t >> 11;
  int idx = t2 % 9;
  int t3 = t2 / 9;
  int kcb = t3 & 1;
  int br = t3 >> 1;
  const float* wgt = br ? w_t : w_e;
  int co = wv * 16 + (lane & 15);
  int ci = kcb * 32 + 8 * (lane >> 4) + j;
  float v = wgt[((size_t)co * 64 + ci) * 9 + idx];
  unsigned u = __float_as_uint(v);
  unsigned short hi = (unsigned short)(u >> 16);
  float rem = v - __uint_as_float(u & 0xffff0000u);
  unsigned short lo = (unsigned short)(__float_as_uint(rem) >> 16);
  whi[t] = hi;
  wlo[t] = lo;
}

// ---------------------------------------------------------------------------
// conv2 (64->64, relu) via MFMA bf16 3-term hi/lo split (unchanged from R7).
// ---------------------------------------------------------------------------
__global__ __launch_bounds__(256) void conv2_mfma_k(
    const float* __restrict__ in_e, const float* __restrict__ in_t,
    const unsigned short* __restrict__ whi, const unsigned short* __restrict__ wlo,
    const float* __restrict__ b_e, const float* __restrict__ b_t,
    float* __restrict__ out_e, float* __restrict__ out_t) {
  const int tile = blockIdx.x;
  const int b = blockIdx.z & 1;
  const int br = blockIdx.z >> 1;
  const float* in = br ? in_t : in_e;
  const float* bias = br ? b_t : b_e;
  float* out = br ? out_t : out_e;

  const int th0 = (tile / 14) * 16, tw0 = (tile % 14) * 16;
  const int tid = threadIdx.x;
  const int wv = tid >> 6, lane = tid & 63;
  const int q = lane >> 4, n = lane & 15;

  __shared__ unsigned short sT[18 * 18 * 72];
  unsigned* sT32 = (unsigned*)sT;

  float4v acc[16];
#pragma unroll
  for (int pr = 0; pr < 16; ++pr) acc[pr] = (float4v)0.f;

  const float* inB = in + (size_t)b * HW * 64;
  const short8* whi8 = (const short8*)whi;
  const short8* wlo8 = (const short8*)wlo;

  for (int kcb = 0; kcb < 2; ++kcb) {
    __syncthreads();
    for (int jj = 0; jj < 21; ++jj) {
      int s = tid + 256 * jj;
      if (s < 5184) {
        int sp = s >> 4, cp = s & 15;
        int lr = sp / 18, lc = sp - lr * 18;
        int gh = th0 + lr - 1, gw = tw0 + lc - 1;
        float vx = 0.f, vy = 0.f;
        if (gh >= 0 && gh < H_ && gw >= 0 && gw < W_) {
          const float2 vv =
              *(const float2*)&inB[((size_t)gh * W_ + gw) * 64 + kcb * 32 + 2 * cp];
          vx = vv.x; vy = vv.y;
        }
        unsigned u0 = __float_as_uint(vx), u1 = __float_as_uint(vy);
        float r0 = vx - __uint_as_float(u0 & 0xffff0000u);
        float r1 = vy - __uint_as_float(u1 & 0xffff0000u);
        unsigned l0 = __float_as_uint(r0) >> 16, l1 = __float_as_uint(r1) >> 16;
        sT32[sp * 36 + cp] = (u0 >> 16) | ((u1 >> 16) << 16);
        sT32[sp * 36 + 16 + cp] = l0 | (l1 << 16);
      }
    }
    __syncthreads();

    short8 Ah[9], Al[9];
    const int abase = (((br * 2 + kcb) * 9) * 4 + wv) * 64 + lane;
#pragma unroll
    for (int idx = 0; idx < 9; ++idx) {
      Ah[idx] = whi8[abase + idx * 256];
      Al[idx] = wlo8[abase + idx * 256];
    }

#pragma unroll
    for (int r = 0; r < 18; ++r) {
      short8 Bh[3], Bl[3];
#pragma unroll
      for (int kx = 0; kx < 3; ++kx) {
        const unsigned short* p = &sT[(r * 18 + n + kx) * 72 + 8 * q];
        Bh[kx] = *(const short8*)p;
        Bl[kx] = *(const short8*)(p + 32);
      }
#pragma unroll
      for (int ky = 0; ky < 3; ++ky) {
        const int pr = r - ky;
        if (pr >= 0 && pr < 16) {
#pragma unroll
          for (int kx = 0; kx < 3; ++kx) {
            const int idx = ky * 3 + kx;
            acc[pr] = __builtin_amdgcn_mfma_f32_16x16x32_bf16(Ah[idx], Bh[kx], acc[pr], 0, 0, 0);
            acc[pr] = __builtin_amdgcn_mfma_f32_16x16x32_bf16(Al[idx], Bh[kx], acc[pr], 0, 0, 0);
            acc[pr] = __builtin_amdgcn_mfma_f32_16x16x32_bf16(Ah[idx], Bl[kx], acc[pr], 0, 0, 0);
          }
        }
      }
    }
  }

  float4v bv = *(const float4v*)&bias[wv * 16 + 4 * q];
#pragma unroll
  for (int pr = 0; pr < 16; ++pr) {
#pragma unroll
    for (int r = 0; r < 4; ++r) {
      int co = wv * 16 + 4 * q + r;
      float v = fmaxf(acc[pr][r] + bv[r], 0.f);
      out[((size_t)b * 64 + co) * HW + (th0 + pr) * W_ + tw0 + n] = v;
    }
  }
}

// ---------------------------------------------------------------------------
// conv3 e+t merged (64->8 from h2e, 64->1 from h2t, no relu). 32x32 tile,
// 4 rows/thread, CIB=2 planes per branch per round, 9 couts (acc[9][4]).
// 36 LDS reads feed 324 FMA per ci -> VALU-bound. Grid (49, B).
// ---------------------------------------------------------------------------
__global__ __launch_bounds__(256) void conv3m_k(
    const float* __restrict__ h2e, const float* __restrict__ h2t,
    const float* __restrict__ w3e, const float* __restrict__ w3t,
    const float* __restrict__ b3e, const float* __restrict__ b3t,
    float* __restrict__ xe, float* __restrict__ ltm) {
  constexpr int TP = 34, CIB = 2;
  constexpr int NST = 2 * CIB * TP * TP;   // 4624 (both branches)
  constexpr int NLD = (NST + 255) / 256;   // 19

  const int tile = blockIdx.x;
  const int b = blockIdx.y;
  const int th0 = (tile / 7) * 32, tw0 = (tile % 7) * 32;
  const int tid = threadIdx.x;
  const int tx = tid & 31, ty = tid >> 5;

  __shared__ float sW[9 * 64 * 12];            // 27648 B
  __shared__ float sT[2][CIB][TP * TP];        // 18496 B

  for (int s = tid; s < 9 * 64 * 12; s += 256) {
    int c = s / (64 * 12);
    int rem = s - c * (64 * 12);
    int ci = rem / 12, r = rem - ci * 12;
    float v = 0.f;
    if (r < 9)
      v = (c < 8) ? w3e[((size_t)c * 64 + ci) * 9 + r]
                  : w3t[(size_t)ci * 9 + r];
    sW[s] = v;
  }

  int po[NLD];
  unsigned okm = 0;
#pragma unroll
  for (int j = 0; j < NLD; ++j) {
    int s = tid + 256 * j;
    int rem2 = s % (CIB * TP * TP);
    int pl = rem2 / (TP * TP), rem = rem2 % (TP * TP);
    int lr = rem / TP, lc = rem - lr * TP;
    int gh = th0 + lr - 1, gw = tw0 + lc - 1;
    bool ok = (s < NST) && gh >= 0 && gh < H_ && gw >= 0 && gw < W_;
    po[j] = ok ? (pl * HW + gh * W_ + gw) : 0;
    if (ok) okm |= (1u << j);
  }

  const float* heB = h2e + (size_t)b * 64 * HW;
  const float* htB = h2t + (size_t)b * 64 * HW;

  float stg[NLD];
#pragma unroll
  for (int j = 0; j < NLD; ++j) {
    int s = tid + 256 * j;
    const float* src = (s < CIB * TP * TP) ? heB : htB;
    float v = src[po[j]];
    stg[j] = ((okm >> j) & 1) ? v : 0.f;
  }

  float acc[9][4];
#pragma unroll
  for (int c = 0; c < 9; ++c) {
    float bv = (c < 8) ? b3e[c] : b3t[0];
#pragma unroll
    for (int r = 0; r < 4; ++r) acc[c][r] = bv;
  }

  for (int cb = 0; cb < 64; cb += CIB) {
    __syncthreads();
#pragma unroll
    for (int j = 0; j < NLD; ++j) {
      int s = tid + 256 * j;
      if (s < NST) ((float*)sT)[s] = stg[j];
    }
    __syncthreads();
    if (cb + CIB < 64) {
      const size_t off = (size_t)(cb + CIB) * HW;
#pragma unroll
      for (int j = 0; j < NLD; ++j) {
        int s = tid + 256 * j;
        const float* src = (s < CIB * TP * TP) ? (heB + off) : (htB + off);
        float v = src[po[j]];
        stg[j] = ((okm >> j) & 1) ? v : 0.f;
      }
    }
#pragma unroll
    for (int ci = 0; ci < CIB; ++ci) {
      float ive[6][3], ivt[6][3];
#pragma unroll
      for (int r = 0; r < 6; ++r)
#pragma unroll
        for (int s2 = 0; s2 < 3; ++s2) {
          ive[r][s2] = sT[0][ci][(4 * ty + r) * 34 + tx + s2];
          ivt[r][s2] = sT[1][ci][(4 * ty + r) * 34 + tx + s2];
        }
#pragma unroll
      for (int c = 0; c < 9; ++c) {
        const float4* wp = (const float4*)&sW[(c * 64 + cb + ci) * 12];
        float4 wa = wp[0], wb = wp[1], wc = wp[2];
        const float (*iv)[3] = (c < 8) ? ive : ivt;
#pragma unroll
        for (int dy = 0; dy < 4; ++dy) {
          acc[c][dy] += iv[dy + 0][0] * wa.x + iv[dy + 0][1] * wa.y +
                        iv[dy + 0][2] * wa.z + iv[dy + 1][0] * wa.w +
                        iv[dy + 1][1] * wb.x + iv[dy + 1][2] * wb.y +
                        iv[dy + 2][0] * wb.z + iv[dy + 2][1] * wb.w +
                        iv[dy + 2][2] * wc.x;
        }
      }
    }
  }

#pragma unroll
  for (int dy = 0; dy < 4; ++dy) {
    int h = th0 + 4 * ty + dy, w = tw0 + tx;
#pragma unroll
    for (int c = 0; c < 8; ++c)
      xe[((size_t)(b * 8 + c) * H_ + h) * W_ + w] = acc[c][dy];
    ltm[(size_t)b * HW + h * W_ + w] = acc[8][dy];
  }
}

// ---------------------------------------------------------------------------
// prep: per (b,n) block (256 thr): write pe row (from xe), yp row (from x),
// reduce sq = ||pe||^2 and lt = mean of 10x10 ltm patch. Replaces
// patches x2 + ltsq.
// ---------------------------------------------------------------------------
__global__ __launch_bounds__(256) void prep_k(const float* __restrict__ xe,
                                              const float* __restrict__ x,
                                              const float* __restrict__ ltm,
                                              float* __restrict__ pe,
                                              float* __restrict__ yp,
                                              float* __restrict__ lt,
                                              float* __restrict__ sq) {
  const int n = blockIdx.x, b = blockIdx.y;
  const int tid = threadIdx.x;
  const int wv = tid >> 6, lane = tid & 63;
  const int q1 = n / N2, q2 = n % N2;
  const int r0 = q1 * 5, c0 = q2 * 5;

  float s = 0.f;
  float* peR = pe + ((size_t)b * N_ + n) * D_;
  float* ypR = yp + ((size_t)b * N_ + n) * D_;
#pragma unroll
  for (int j = 0; j < 4; ++j) {
    int d = tid + 256 * j;
    if (d < D_) {
      int c = d / 100;
      int rr = (d / 10) % 10;
      int cc = d % 10;
      size_t si = ((size_t)(b * 8 + c) * H_ + r0 + rr) * W_ + c0 + cc;
      float ve = xe[si];
      float vx = x[si];
      peR[d] = ve;
      ypR[d] = vx;
      s += ve * ve;
    }
  }
  float t = 0.f;
  if (tid < 100) t = ltm[(size_t)b * HW + (r0 + tid / 10) * W_ + c0 + tid % 10];

#pragma unroll
  for (int off = 32; off > 0; off >>= 1) {
    s += __shfl_xor(s, off);
    t += __shfl_xor(t, off);
  }
  __shared__ float rs[4], rt[4];
  if (lane == 0) { rs[wv] = s; rt[wv] = t; }
  __syncthreads();
  if (tid == 0) {
    sq[b * N_ + n] = rs[0] + rs[1] + rs[2] + rs[3];
    lt[b * N_ + n] = (rt[0] + rt[1] + rt[2] + rt[3]) * 0.01f;
  }
}

// ---------------------------------------------------------------------------
// attn stage 1: 256-thr blocks, one wave per query (4 queries/block), no LDS:
// dot results kept in registers via butterfly-broadcast + lane==m select.
// ---------------------------------------------------------------------------
__global__ __launch_bounds__(256) void attn_w_k(const float* __restrict__ pe,
                                                const float* __restrict__ lt,
                                                const float* __restrict__ sq,
                                                float* __restrict__ wk) {
  const int wv = threadIdx.x >> 6, lane = threadIdx.x & 63;
  const int n = blockIdx.x * 4 + wv;
  if (n >= N_) return;
  const int b = blockIdx.y;
  const int q1 = n / N2, q2 = n % N2;

  const float* peB = pe + (size_t)b * N_ * D_;
  const float* qrow = peB + (size_t)n * D_;
  float q[13];
#pragma unroll
  for (int t = 0; t < 13; ++t) {
    int s = t * 64 + lane;
    q[t] = (s < D_) ? qrow[s] : 0.f;
  }

  const float sqn = sq[b * N_ + n];
  const float itemp = expf(-lt[b * N_ + n]);
  float gm = -INFINITY;

  for (int o1 = 0; o1 < 7; ++o1) {
    int c1 = clampi(q1 + o1 - 3, 0, N1 - 1);
    const float* rowb = peB + (size_t)(c1 * N2) * D_;
#pragma unroll
    for (int o2 = 0; o2 < 7; ++o2) {
      int c2 = clampi(q2 + o2 - 3, 0, N2 - 1);
      int cn = c1 * N2 + c2;
      const float* crow = rowb + (size_t)c2 * D_;
      float a = 0.f;
#pragma unroll
      for (int t = 0; t < 13; ++t) {
        float v;
        if (t < 12) v = crow[t * 64 + lane];
        else v = (lane < 32) ? crow[768 + lane] : 0.f;
        a += q[t] * v;
      }
#pragma unroll
      for (int off = 32; off > 0; off >>= 1) a += __shfl_xor(a, off);
      float Dv = -(sqn + sq[b * N_ + cn] - 2.f * a);
      float lg = (cn == n) ? -1e9f : Dv * itemp;
      const int m = o1 * 7 + o2;
      gm = (lane == m) ? lg : gm;
    }
  }

  float cur = (lane < M_) ? gm : -INFINITY;
  float* wrow = wk + (size_t)(b * N_ + n) * (M_ * K_);
#pragma unroll
  for (int k = 0; k < K_; ++k) {
    float mx = cur;
#pragma unroll
    for (int off = 32; off > 0; off >>= 1) mx = fmaxf(mx, __shfl_xor(mx, off));
    float e = (lane < M_) ? expf(cur - mx) : 0.f;
    float ssum = e;
#pragma unroll
    for (int off = 32; off > 0; off >>= 1) ssum += __shfl_xor(ssum, off);
    float w = e / ssum;
    if (lane < M_) wrow[lane * K_ + k] = w;
    cur += log1pf(-fminf(w, 1.f - 1e-6f));
  }
}

// ---------------------------------------------------------------------------
// attn stage 2: 256-thr blocks, one wave per 64-d slice (4 slices/block).
// Grid (N, 4, B); slices 13..15 exit immediately (no barriers in body).
// ---------------------------------------------------------------------------
__global__ __launch_bounds__(256) void attn_pv_k(const float* __restrict__ yp,
                                                 const float* __restrict__ wk,
                                                 float* __restrict__ nb) {
  const int wv = threadIdx.x >> 6, lane = threadIdx.x & 63;
  const int n = blockIdx.x;
  const int b = blockIdx.z;
  const int sl = blockIdx.y * 4 + wv;
  const int d = sl * 64 + lane;
  if (d >= D_) return;
  const int q1 = n / N2, q2 = n % N2;

  const float* ypB = yp + (size_t)b * N_ * D_;
  const float* wrow = wk + (size_t)(b * N_ + n) * (M_ * K_);

  float acc[K_];
#pragma unroll
  for (int k = 0; k < K_; ++k) acc[k] = 0.f;

#pragma unroll
  for (int o1 = 0; o1 < 7; ++o1) {
    int c1 = clampi(q1 + o1 - 3, 0, N1 - 1);
#pragma unroll
    for (int o2 = 0; o2 < 7; ++o2) {
      int c2 = clampi(q2 + o2 - 3, 0, N2 - 1);
      int cn = c1 * N2 + c2;
      float y = ypB[(size_t)cn * D_ + d];
      const int m = o1 * 7 + o2;
#pragma unroll
      for (int k = 0; k < K_; ++k) acc[k] += wrow[m * K_ + k] * y;
    }
  }
#pragma unroll
  for (int k = 0; k < K_; ++k)
    nb[(((size_t)k * B_ + b) * N_ + n) * D_ + d] = acc[k];
}

// ---------------------------------------------------------------------------
// Fused output: channels 0..7 copy x; channels 8..63 fold-gather from nb.
// ---------------------------------------------------------------------------
__global__ __launch_bounds__(256) void foldcopy_k(const float* __restrict__ x,
                                                  const float* __restrict__ nb,
                                                  float* __restrict__ out) {
  int i = blockIdx.x * 256 + threadIdx.x;
  constexpr int CT = CIN * (K_ + 1);  // 64
  constexpr int TOT = B_ * CT * HW;
  if (i >= TOT) return;
  int w = i % W_;
  int h = (i / W_) % H_;
  int c64 = (i / HW) % CT;
  int b = i / (HW * CT);
  if (c64 < CIN) {
    out[i] = x[((size_t)b * CIN + c64) * HW + h * W_ + w];
    return;
  }
  int k = (c64 - CIN) >> 3, c = (c64 - CIN) & 7;
  int q1lo = max(0, (h - 5) / 5), q1hi = min(N1 - 1, h / 5);
  int q2lo = max(0, (w - 5) / 5), q2hi = min(N2 - 1, w / 5);
  float val = 0.f;
  int cnt = 0;
  for (int q1 = q1lo; q1 <= q1hi; ++q1)
    for (int q2 = q2lo; q2 <= q2hi; ++q2) {
      int i0 = h - 5 * q1, j0 = w - 5 * q2;
      int nn = q1 * N2 + q2;
      val += nb[(((size_t)k * B_ + b) * N_ + nn) * D_ + c * 100 + i0 * 10 + j0];
      ++cnt;
    }
  out[i] = (cnt > 0) ? val / (float)cnt : 0.f;
}

extern "C" void kernel_launch(void* const* d_in, const int* in_sizes, int n_in,
                              void* d_out, int out_size, void* d_ws,
                              size_t ws_size, hipStream_t stream) {
  const float* x   = (const float*)d_in[0];
  const float* w1e = (const float*)d_in[1];
  const float* b1e = (const float*)d_in[2];
  const float* w2e = (const float*)d_in[3];
  const float* b2e = (const float*)d_in[4];
  const float* w3e = (const float*)d_in[5];
  const float* b3e = (const float*)d_in[6];
  const float* w1t = (const float*)d_in[7];
  const float* b1t = (const float*)d_in[8];
  const float* w2t = (const float*)d_in[9];
  const float* b2t = (const float*)d_in[10];
  const float* w3t = (const float*)d_in[11];
  const float* b3t = (const float*)d_in[12];

  float* ws  = (float*)d_ws;
  float* out = (float*)d_out;

  float* h1e = ws + OFF_H1E;   // channels-last
  float* h1t = ws + OFF_H1T;   // channels-last
  float* h2e = ws + OFF_H2E;   // NCHW
  float* h2t = ws + OFF_H2T;   // NCHW
  float* wkb = ws + OFF_WK;
  float* nb  = ws + OFF_NB;
  float* xe  = ws + OFF_XE;
  float* ltm = ws + OFF_LTM;
  float* pe  = ws + OFF_PE;
  float* yp  = ws + OFF_YP;
  float* lt  = ws + OFF_LT;
  float* sqv = ws + OFF_SQ;
  unsigned short* whi = (unsigned short*)(ws + OFF_XE);  // consumed before xe written
  unsigned short* wlo = whi + WPREP_N;

  // conv2 weight prep
  wprep_k<<<(WPREP_N + 255) / 256, 256, 0, stream>>>(w2e, w2t, whi, wlo);
  // conv1 (8 -> 64, relu), e+t in one dispatch, channels-last output
  conv1m_k<<<dim3(8, 49, 4), 256, 0, stream>>>(x, w1e, b1e, h1e, w1t, b1t, h1t);
  // conv2 (64 -> 64, relu) via MFMA, both branches + batches in one dispatch
  conv2_mfma_k<<<dim3(196, 1, 4), 256, 0, stream>>>(h1e, h1t, whi, wlo, b2e, b2t, h2e, h2t);
  // conv3 (64 -> 8 + 64 -> 1) merged
  conv3m_k<<<dim3(49, B_), 256, 0, stream>>>(h2e, h2t, w3e, w3t, b3e, b3t, xe, ltm);
  // patches + norms + log-temp means fused
  prep_k<<<dim3(N_, B_), 256, 0, stream>>>(xe, x, ltm, pe, yp, lt, sqv);
  // attention stage 1: weights
  attn_w_k<<<dim3((N_ + 3) / 4, B_), 256, 0, stream>>>(pe, lt, sqv, wkb);
  // attention stage 2: weighted neighbor sums
  attn_pv_k<<<dim3(N_, 4, B_), 256, 0, stream>>>(yp, wkb, nb);
  // fused fold + x passthrough
  constexpr int FT = B_ * CIN * (K_ + 1) * HW;
  foldcopy_k<<<(FT + 255) / 256, 256, 0, stream>>>(x, nb, out);
}